// Round 12
// baseline (288.723 us; speedup 1.0000x reference)
//
#include <hip/hip_runtime.h>
#include <hip/hip_bf16.h>
#include <math.h>

#define B_    4
#define T_    1536
#define DIN_  512
#define D_    512
#define K_    2
#define H_    8
#define BAND_ 24
#define DH_   64
#define M_    (B_*T_)      // 6144 rows
#define M2_   (2*M_)       // both streams batched
#define ALPHA_ 6.0f
#define BETA_  0.5f
#define EPS_   1e-5f

using bf8  = __attribute__((ext_vector_type(8))) short;   // 8 bf16 (4 VGPRs)
using f32x4 = __attribute__((ext_vector_type(4))) float;  // 4 fp32 acc

__device__ __forceinline__ void async_copy16(const void* g, void* l) {
  __builtin_amdgcn_global_load_lds(
      (const __attribute__((address_space(1))) unsigned int*)g,
      (__attribute__((address_space(3))) unsigned int*)l, 16, 0, 0);
}

__device__ __forceinline__ short f2bf(float v) {
  __hip_bfloat16 h = (__hip_bfloat16)v;
  return *(short*)&h;
}
__device__ __forceinline__ float bf2f(short s) {
  union { unsigned u; float f; } c;
  c.u = ((unsigned)(unsigned short)s) << 16;
  return c.f;
}
// XOR-swizzle of 16B chunks within each 64-element column block (bank-conflict fix)
__device__ __forceinline__ int swz64(int row, int col) {
  return (col & ~63) | ((((col >> 3) ^ row) & 7) << 3) | (col & 7);
}
// tanh-form gelu, 7 VALU (2*log2e folded into polynomial), max err ~1e-3
__device__ __forceinline__ float fast_gelu(float x) {
  const float t = fmaf(0.1029504013f, x * x, 2.3021170686f);  // (a x^2 + b)*2*log2e
  const float e = __builtin_amdgcn_exp2f(x * t);              // e^{2u}
  const float r = __builtin_amdgcn_rcpf(e + 1.0f);
  return fmaf(-x, r, x);
}
// 64-lane butterfly sum
__device__ __forceinline__ float wave_sum(float s) {
#pragma unroll
  for (int o = 1; o < 64; o <<= 1) s += __shfl_xor(s, o);
  return s;
}

// ---------------- bf16 MFMA GEMM: C = A[M,Kd] @ Bt[N,Kd]^T + bias (+res) (+gelu) (+tag)
// A and Bt chunk-swizzled (per 64-element K-block). FLAGS: 1=gelu, 2=bf16 out,
// 4=swizzled out, 8=bf16 residual, 16=fp32 residual, 32=speaker tag.
// TRANSPOSED-ACC epilogue: mfma(bF, aF) => out row = l15, col = quad*4+reg.
template<int BM, int BN, int NI, int NJ, int BK, int FLAGS>
__global__ __launch_bounds__(256) void gemm_bt_t(
    const short* __restrict__ A, const short* __restrict__ Bt,
    const float* __restrict__ bias, const void* __restrict__ res,
    const float* __restrict__ tag2,
    void* __restrict__ Cout, int M, int N, int Kd, int gx) {
  constexpr int CPR  = BK / 8;          // 16B chunks per row
  constexpr int CLOG = (BK == 128) ? 4 : 3;
  __shared__ short lA[BM * BK];
  __shared__ short lB[BN * BK];
  const int gy   = gridDim.x / gx;
  const int xcd  = blockIdx.x & 7;
  const int seq  = blockIdx.x >> 3;
  const int rpx  = gy >> 3;                 // row-tiles per XCD
  const int by   = xcd * rpx + seq / gx;
  const int bx   = seq % gx;
  const int tid  = threadIdx.x;
  const int wave = tid >> 6, lane = tid & 63;
  const int block_m = by * BM, block_n = bx * BN;
  const int wm = (wave & 1) * (BM / 2), wn = (wave >> 1) * (BN / 2);
  const int l15 = lane & 15, quad = lane >> 4, l7 = lane & 7;
  f32x4 acc[NI][NJ] = {};

  for (int k0 = 0; k0 < Kd; k0 += BK) {
    __syncthreads();               // previous step's LDS reads complete
#pragma unroll
    for (int i = 0; i < (BM * CPR) / 256; ++i) {
      const int cb = wave * (BM * CPR / 4) + i * 64;
      const int c  = cb + lane;                 // chunk of 8 bf16
      async_copy16(A + (size_t)(block_m + (c >> CLOG)) * Kd + k0 + (c & (CPR - 1)) * 8,
                   &lA[cb * 8]);
    }
#pragma unroll
    for (int i = 0; i < (BN * CPR) / 256; ++i) {
      const int cb = wave * (BN * CPR / 4) + i * 64;
      const int c  = cb + lane;
      async_copy16(Bt + (size_t)(block_n + (c >> CLOG)) * Kd + k0 + (c & (CPR - 1)) * 8,
                   &lB[cb * 8]);
    }
    __syncthreads();               // barrier drains vmcnt => LDS tiles ready
#pragma unroll
    for (int ks = 0; ks < BK / 32; ++ks) {
      const int kidx = ks * 4 + quad;
      const int koff = ((kidx & ~7) | ((kidx ^ l7) & 7)) << 3;
      bf8 af[NI], bfr[NJ];
#pragma unroll
      for (int i = 0; i < NI; ++i)
        af[i] = *(const bf8*)&lA[(wm + i * 16 + l15) * BK + koff];
#pragma unroll
      for (int j = 0; j < NJ; ++j)
        bfr[j] = *(const bf8*)&lB[(wn + j * 16 + l15) * BK + koff];
#pragma unroll
      for (int i = 0; i < NI; ++i)
#pragma unroll
        for (int j = 0; j < NJ; ++j)
          acc[i][j] = __builtin_amdgcn_mfma_f32_16x16x32_bf16(bfr[j], af[i], acc[i][j], 0, 0, 0);
    }
  }

  const int half = M >> 1;
#pragma unroll
  for (int i = 0; i < NI; ++i) {
    const int row  = block_m + wm + i * 16 + l15;
    const size_t rowN = (size_t)row * N;
    const int toff = (row >= half) ? N : 0;
#pragma unroll
    for (int j = 0; j < NJ; ++j) {
      const int colb = block_n + wn + j * 16 + quad * 4;
      const float4 bb = *(const float4*)&bias[colb];
      float v0 = acc[i][j][0] + bb.x;
      float v1 = acc[i][j][1] + bb.y;
      float v2 = acc[i][j][2] + bb.z;
      float v3 = acc[i][j][3] + bb.w;
      if constexpr (FLAGS & 8) {
        const short4 rv = *(const short4*)&((const short*)res)[rowN + colb];
        v0 += bf2f(rv.x); v1 += bf2f(rv.y); v2 += bf2f(rv.z); v3 += bf2f(rv.w);
      }
      if constexpr (FLAGS & 16) {
        const float4 rv = *(const float4*)&((const float*)res)[rowN + colb];
        v0 += rv.x; v1 += rv.y; v2 += rv.z; v3 += rv.w;
      }
      if constexpr (FLAGS & 32) {
        const float4 tg = *(const float4*)&tag2[toff + colb];
        v0 += tg.x; v1 += tg.y; v2 += tg.z; v3 += tg.w;
      }
      if constexpr (FLAGS & 1) {
        v0 = fast_gelu(v0); v1 = fast_gelu(v1);
        v2 = fast_gelu(v2); v3 = fast_gelu(v3);
      }
      if constexpr (FLAGS & 2) {
        const int oc = (FLAGS & 4) ? swz64(row, colb) : colb;
        short4 o;
        o.x = f2bf(v0); o.y = f2bf(v1); o.z = f2bf(v2); o.w = f2bf(v3);
        *(short4*)&((short*)Cout)[rowN + oc] = o;
      } else {
        float4 o; o.x = v0; o.y = v1; o.z = v2; o.w = v3;
        *(float4*)&((float*)Cout)[rowN + colb] = o;
      }
    }
  }
}

// ---------------- FFN GEMM: 512-thread 8-wave 256x64 tile, BK=64.
// Mechanism (CONFIRMED R11 on W1: 47.8 -> <42.6 us): 8 waves/block at only
// 40KB LDS raises resident waves/CU 2-4x vs the 256-thread configs (which
// measured 12-33% occupancy) — more waves hide the stage->drain latency.
// Conflict-free BK=64 read pattern. FLAGS: 1=gelu, 4=swizzled out,
// 8=bf16 residual, 32=speaker tag. bf16 out always. M fixed = M2_.
template<int FLAGS>
__global__ __launch_bounds__(512) void gemm_ffn_t(
    const short* __restrict__ A, const short* __restrict__ Bt,
    const float* __restrict__ bias, const short* __restrict__ res,
    const float* __restrict__ tag2, short* __restrict__ Cout,
    int N, int Kd, int gx) {
  __shared__ short lA[256 * 64];
  __shared__ short lB[64 * 64];
  const int gy   = gridDim.x / gx;
  const int xcd  = blockIdx.x & 7;
  const int seq  = blockIdx.x >> 3;
  const int rpx  = gy >> 3;
  const int by   = xcd * rpx + seq / gx;
  const int bx   = seq % gx;
  const int tid  = threadIdx.x;
  const int wave = tid >> 6, lane = tid & 63;
  const int block_m = by * 256, block_n = bx * 64;
  const int wm = (wave & 3) * 64, wn = (wave >> 2) * 32;
  const int l15 = lane & 15, quad = lane >> 4, l7 = lane & 7;
  f32x4 acc[4][2] = {};

  for (int k0 = 0; k0 < Kd; k0 += 64) {
    __syncthreads();
#pragma unroll
    for (int i = 0; i < 4; ++i) {
      const int cb = wave * 256 + i * 64;
      const int c  = cb + lane;
      async_copy16(A + (size_t)(block_m + (c >> 3)) * Kd + k0 + (c & 7) * 8,
                   &lA[cb * 8]);
    }
    {
      const int cb = wave * 64;
      const int c  = cb + lane;
      async_copy16(Bt + (size_t)(block_n + (c >> 3)) * Kd + k0 + (c & 7) * 8,
                   &lB[cb * 8]);
    }
    __syncthreads();
#pragma unroll
    for (int ks = 0; ks < 2; ++ks) {
      const int koff = (((ks * 4 + quad) ^ l7) << 3);
      bf8 af[4], bfr[2];
#pragma unroll
      for (int i = 0; i < 4; ++i)
        af[i] = *(const bf8*)&lA[(wm + i * 16 + l15) * 64 + koff];
#pragma unroll
      for (int j = 0; j < 2; ++j)
        bfr[j] = *(const bf8*)&lB[(wn + j * 16 + l15) * 64 + koff];
#pragma unroll
      for (int i = 0; i < 4; ++i)
#pragma unroll
        for (int j = 0; j < 2; ++j)
          acc[i][j] = __builtin_amdgcn_mfma_f32_16x16x32_bf16(bfr[j], af[i], acc[i][j], 0, 0, 0);
    }
  }

#pragma unroll
  for (int i = 0; i < 4; ++i) {
    const int row  = block_m + wm + i * 16 + l15;
    const size_t rowN = (size_t)row * N;
    const int toff = (row >= M_) ? N : 0;
#pragma unroll
    for (int j = 0; j < 2; ++j) {
      const int colb = block_n + wn + j * 16 + quad * 4;
      const float4 bb = *(const float4*)&bias[colb];
      float v0 = acc[i][j][0] + bb.x;
      float v1 = acc[i][j][1] + bb.y;
      float v2 = acc[i][j][2] + bb.z;
      float v3 = acc[i][j][3] + bb.w;
      if constexpr (FLAGS & 8) {
        const short4 rv = *(const short4*)&res[rowN + colb];
        v0 += bf2f(rv.x); v1 += bf2f(rv.y); v2 += bf2f(rv.z); v3 += bf2f(rv.w);
      }
      if constexpr (FLAGS & 32) {
        const float4 tg = *(const float4*)&tag2[toff + colb];
        v0 += tg.x; v1 += tg.y; v2 += tg.z; v3 += tg.w;
      }
      if constexpr (FLAGS & 1) {
        v0 = fast_gelu(v0); v1 = fast_gelu(v1);
        v2 = fast_gelu(v2); v3 = fast_gelu(v3);
      }
      const int oc = (FLAGS & 4) ? swz64(row, colb) : colb;
      short4 o;
      o.x = f2bf(v0); o.y = f2bf(v1); o.z = f2bf(v2); o.w = f2bf(v3);
      *(short4*)&Cout[rowN + oc] = o;
    }
  }
}

// ---- shared 128x128 FLAGS=2 core (bf16 out, bias only), BK=64 single-buffer
// (round-3 proven; used by the dual KV/Q kernel)
__device__ __forceinline__ void gemm128_core(
    const short* __restrict__ A, const short* __restrict__ Bt,
    const float* __restrict__ bias, short* __restrict__ Cout,
    int N, int Kd, int bid, int gx, int gy, short* lA, short* lB) {
  const int xcd  = bid & 7;
  const int seq  = bid >> 3;
  const int rpx  = gy >> 3;
  const int by   = xcd * rpx + seq / gx;
  const int bx   = seq % gx;
  const int tid  = threadIdx.x;
  const int wave = tid >> 6, lane = tid & 63;
  const int block_m = by * 128, block_n = bx * 128;
  const int wm = (wave & 1) * 64, wn = (wave >> 1) * 64;
  const int l15 = lane & 15, quad = lane >> 4, l7 = lane & 7;
  f32x4 acc[4][4] = {};

  for (int k0 = 0; k0 < Kd; k0 += 64) {
    __syncthreads();
#pragma unroll
    for (int i = 0; i < 4; ++i) {
      const int cb = wave * 256 + i * 64;
      const int c  = cb + lane;
      async_copy16(A + (size_t)(block_m + (c >> 3)) * Kd + k0 + (c & 7) * 8,
                   &lA[cb * 8]);
    }
#pragma unroll
    for (int i = 0; i < 4; ++i) {
      const int cb = wave * 256 + i * 64;
      const int c  = cb + lane;
      async_copy16(Bt + (size_t)(block_n + (c >> 3)) * Kd + k0 + (c & 7) * 8,
                   &lB[cb * 8]);
    }
    __syncthreads();
#pragma unroll
    for (int ks = 0; ks < 2; ++ks) {
      bf8 af[4], bfr[4];
#pragma unroll
      for (int i = 0; i < 4; ++i)
        af[i] = *(const bf8*)&lA[(wm + i * 16 + l15) * 64 + (((ks * 4 + quad) ^ l7) << 3)];
#pragma unroll
      for (int j = 0; j < 4; ++j)
        bfr[j] = *(const bf8*)&lB[(wn + j * 16 + l15) * 64 + (((ks * 4 + quad) ^ l7) << 3)];
#pragma unroll
      for (int i = 0; i < 4; ++i)
#pragma unroll
        for (int j = 0; j < 4; ++j)
          acc[i][j] = __builtin_amdgcn_mfma_f32_16x16x32_bf16(bfr[j], af[i], acc[i][j], 0, 0, 0);
    }
  }

#pragma unroll
  for (int i = 0; i < 4; ++i) {
    const int row  = block_m + wm + i * 16 + l15;
    const size_t rowN = (size_t)row * N;
#pragma unroll
    for (int j = 0; j < 4; ++j) {
      const int colb = block_n + wn + j * 16 + quad * 4;
      const float4 bb = *(const float4*)&bias[colb];
      short4 o;
      o.x = f2bf(acc[i][j][0] + bb.x);
      o.y = f2bf(acc[i][j][1] + bb.y);
      o.z = f2bf(acc[i][j][2] + bb.z);
      o.w = f2bf(acc[i][j][3] + bb.w);
      *(short4*)&Cout[rowN + colb] = o;
    }
  }
}

// ---- dual GEMM: first nb0 blocks = GEMM0 (KV), rest = GEMM1 (Q). One launch,
// perfect 3-blocks/CU balance instead of two 1.5-blocks/CU launches with tails.
__global__ __launch_bounds__(256) void gemm_dual_k(
    const short* __restrict__ A0, const short* __restrict__ Bt0,
    const float* __restrict__ bias0, short* __restrict__ C0, int N0, int nb0, int gx0,
    const short* __restrict__ A1, const short* __restrict__ Bt1,
    const float* __restrict__ bias1, short* __restrict__ C1, int N1, int gx1) {
  __shared__ short lA[128 * 64];
  __shared__ short lB[128 * 64];
  const int bid = blockIdx.x;
  if (bid < nb0) {
    gemm128_core(A0, Bt0, bias0, C0, N0, D_, bid, gx0, nb0 / gx0, lA, lB);
  } else {
    const int b1 = bid - nb0;
    const int nb1 = gridDim.x - nb0;
    gemm128_core(A1, Bt1, bias1, C1, N1, D_, b1, gx1, nb1 / gx1, lA, lB);
  }
}

// ---------------- merged prep: x_m cast (swizzled) + 7 weight transposes + bias concat
__device__ __forceinline__ void tconv_tile(const float* __restrict__ W,
                                           short* __restrict__ Wt, int K, int N,
                                           int bx, int by, int tid, float (*s)[33]) {
  const int tx = tid & 31, ty = tid >> 5;
  const int k0 = by * 32, n0 = bx * 32;
#pragma unroll
  for (int r = 0; r < 4; ++r)
    s[ty * 4 + r][tx] = W[(size_t)(k0 + ty * 4 + r) * N + n0 + tx];
  __syncthreads();
#pragma unroll
  for (int r = 0; r < 4; ++r) {
    const int n = n0 + ty * 4 + r;
    Wt[(size_t)n * K + swz64(n, k0 + tx)] = f2bf(s[tx][ty * 4 + r]);
  }
}

__global__ __launch_bounds__(256) void prep_k(
    const float* __restrict__ x_m, short* __restrict__ xb,
    const float* __restrict__ W_in, short* __restrict__ WtIn,
    const float* __restrict__ Wq,  short* __restrict__ WtQ,
    const float* __restrict__ Wk,  const float* __restrict__ Wv,
    short* __restrict__ WtKV,
    const float* __restrict__ Wo,  short* __restrict__ WtO,
    const float* __restrict__ W1,  short* __restrict__ Wt1,
    const float* __restrict__ W2,  short* __restrict__ Wt2,
    const float* __restrict__ bk,  const float* __restrict__ bv,
    float* __restrict__ bkv) {
  __shared__ float s[32][33];
  const int blk = blockIdx.x, tid = threadIdx.x;
  if (blk < 3072) {                       // x_m -> bf16 swizzled (float4 per thread)
    const int e = (blk * 256 + tid) * 4;
    const int row = e >> 9, col = e & 511;
    const float4 v = *(const float4*)&x_m[e];
    short4 o;
    o.x = f2bf(v.x); o.y = f2bf(v.y); o.z = f2bf(v.z); o.w = f2bf(v.w);
    *(short4*)&xb[((size_t)row << 9) | swz64(row, col)] = o;
  } else if (blk < 3328) {                // W_in [512,512]
    const int t = blk - 3072; tconv_tile(W_in, WtIn, DIN_, D_, t & 15, t >> 4, tid, s);
  } else if (blk < 3584) {                // Wq
    const int t = blk - 3328; tconv_tile(Wq, WtQ, D_, D_, t & 15, t >> 4, tid, s);
  } else if (blk < 3840) {                // Wk -> WtKV[0:512]
    const int t = blk - 3584; tconv_tile(Wk, WtKV, D_, D_, t & 15, t >> 4, tid, s);
  } else if (blk < 4096) {                // Wv -> WtKV[512:1024]
    const int t = blk - 3840; tconv_tile(Wv, WtKV + (size_t)D_ * D_, D_, D_, t & 15, t >> 4, tid, s);
  } else if (blk < 4352) {                // Wo
    const int t = blk - 4096; tconv_tile(Wo, WtO, D_, D_, t & 15, t >> 4, tid, s);
  } else if (blk < 5376) {                // W1 [512,2048]: gx=64
    const int t = blk - 4352; tconv_tile(W1, Wt1, D_, 4 * D_, t & 63, t >> 6, tid, s);
  } else if (blk < 6400) {                // W2 [2048,512]: gx=16
    const int t = blk - 5376; tconv_tile(W2, Wt2, 4 * D_, D_, t & 15, t >> 4, tid, s);
  } else {                                // bias concat (4 blocks)
    const int i = (blk - 6400) * 256 + tid;
    bkv[i] = (i < D_) ? bk[i] : bv[i - D_];
  }
}

// ---------------- LayerNorm, bf16 in: out(bf16, swizzled) = LN(in) * g + b
// one 64-lane wave per row (4 rows/block), bf8 loads, shfl reduce, no barriers
__global__ __launch_bounds__(256) void ln_bf_k(const short* __restrict__ in,
                                               const float* __restrict__ g,
                                               const float* __restrict__ b,
                                               short* __restrict__ out) {
  const int row  = blockIdx.x * 4 + (threadIdx.x >> 6);
  const int lane = threadIdx.x & 63;
  const int c0   = lane * 8;
  const bf8 xv = *(const bf8*)&in[(size_t)row * D_ + c0];
  float v[8];
  float s = 0.0f;
#pragma unroll
  for (int e = 0; e < 8; ++e) { v[e] = bf2f(xv[e]); s += v[e]; }
  const float mean = wave_sum(s) * (1.0f / D_);
  float s2 = 0.0f;
#pragma unroll
  for (int e = 0; e < 8; ++e) { v[e] -= mean; s2 += v[e] * v[e]; }
  const float inv = rsqrtf(wave_sum(s2) * (1.0f / D_) + EPS_);
  const float4 g0 = *(const float4*)&g[c0];
  const float4 g1 = *(const float4*)&g[c0 + 4];
  const float4 b0 = *(const float4*)&b[c0];
  const float4 b1 = *(const float4*)&b[c0 + 4];
  bf8 o;
  o[0] = f2bf(v[0] * inv * g0.x + b0.x);
  o[1] = f2bf(v[1] * inv * g0.y + b0.y);
  o[2] = f2bf(v[2] * inv * g0.z + b0.z);
  o[3] = f2bf(v[3] * inv * g0.w + b0.w);
  o[4] = f2bf(v[4] * inv * g1.x + b1.x);
  o[5] = f2bf(v[5] * inv * g1.y + b1.y);
  o[6] = f2bf(v[6] * inv * g1.z + b1.z);
  o[7] = f2bf(v[7] * inv * g1.w + b1.w);
  *(bf8*)&out[(size_t)row * D_ + swz64(row, c0)] = o;
}

// ---------------- merged KV-LN + gate/Q-LN: rows [0,M) = ln_kv(X) -> KVb (swizzled);
// rows [M,3M) = gate+ln_q: Xk (bf16 unswz) + LNq (swizzled). One launch, no tail.
__global__ __launch_bounds__(256) void ln_gate_k(
    const short* __restrict__ X, const float* __restrict__ Ain,
    const float* __restrict__ gkv, const float* __restrict__ bkvp,
    const float* __restrict__ gq, const float* __restrict__ bqp,
    short* __restrict__ KVb, short* __restrict__ Xk, short* __restrict__ LNq) {
  const int row  = blockIdx.x * 4 + (threadIdx.x >> 6);
  const int lane = threadIdx.x & 63;
  const int c0   = lane * 8;
  float v[8];
  float s = 0.0f;
  if (row < M_) {
    const bf8 xv = *(const bf8*)&X[(size_t)row * D_ + c0];
#pragma unroll
    for (int e = 0; e < 8; ++e) { v[e] = bf2f(xv[e]); s += v[e]; }
    const float mean = wave_sum(s) * (1.0f / D_);
    float s2 = 0.0f;
#pragma unroll
    for (int e = 0; e < 8; ++e) { v[e] -= mean; s2 += v[e] * v[e]; }
    const float inv = rsqrtf(wave_sum(s2) * (1.0f / D_) + EPS_);
    const float4 g0 = *(const float4*)&gkv[c0];
    const float4 g1 = *(const float4*)&gkv[c0 + 4];
    const float4 b0 = *(const float4*)&bkvp[c0];
    const float4 b1 = *(const float4*)&bkvp[c0 + 4];
    bf8 o;
    o[0] = f2bf(v[0] * inv * g0.x + b0.x);
    o[1] = f2bf(v[1] * inv * g0.y + b0.y);
    o[2] = f2bf(v[2] * inv * g0.z + b0.z);
    o[3] = f2bf(v[3] * inv * g0.w + b0.w);
    o[4] = f2bf(v[4] * inv * g1.x + b1.x);
    o[5] = f2bf(v[5] * inv * g1.y + b1.y);
    o[6] = f2bf(v[6] * inv * g1.z + b1.z);
    o[7] = f2bf(v[7] * inv * g1.w + b1.w);
    *(bf8*)&KVb[(size_t)row * D_ + swz64(row, c0)] = o;
  } else {
    const int r2 = row - M_;            // [0, 2M)
    const int kk = r2 / M_, rm = r2 % M_;
    const float a = Ain[(size_t)rm * K_ + kk];
    const float w = __builtin_amdgcn_rcpf(1.0f + __expf(-ALPHA_ * (a - BETA_)));
    const bf8 xv = *(const bf8*)&X[(size_t)rm * D_ + c0];
    bf8 xo;
#pragma unroll
    for (int e = 0; e < 8; ++e) {
      v[e] = bf2f(xv[e]) * w;
      xo[e] = f2bf(v[e]);
      s += v[e];
    }
    *(bf8*)&Xk[(size_t)r2 * D_ + c0] = xo;
    const float mean = wave_sum(s) * (1.0f / D_);
    float s2 = 0.0f;
#pragma unroll
    for (int e = 0; e < 8; ++e) { v[e] -= mean; s2 += v[e] * v[e]; }
    const float inv = rsqrtf(wave_sum(s2) * (1.0f / D_) + EPS_);
    const float4 g0 = *(const float4*)&gq[c0];
    const float4 g1 = *(const float4*)&gq[c0 + 4];
    const float4 b0 = *(const float4*)&bqp[c0];
    const float4 b1 = *(const float4*)&bqp[c0 + 4];
    bf8 o;
    o[0] = f2bf(v[0] * inv * g0.x + b0.x);
    o[1] = f2bf(v[1] * inv * g0.y + b0.y);
    o[2] = f2bf(v[2] * inv * g0.z + b0.z);
    o[3] = f2bf(v[3] * inv * g0.w + b0.w);
    o[4] = f2bf(v[4] * inv * g1.x + b1.x);
    o[5] = f2bf(v[5] * inv * g1.y + b1.y);
    o[6] = f2bf(v[6] * inv * g1.z + b1.z);
    o[7] = f2bf(v[7] * inv * g1.w + b1.w);
    *(bf8*)&LNq[(size_t)r2 * D_ + swz64(r2, c0)] = o;
  }
}

// ---------------- final LN: in = T2b (y+h2+tag, bf16); scatter to concat layout (fp32)
__global__ __launch_bounds__(256) void final_ln_k(
    const short* __restrict__ t2, const float* __restrict__ g,
    const float* __restrict__ b, float* __restrict__ out) {
  const int row  = blockIdx.x * 4 + (threadIdx.x >> 6);
  const int lane = threadIdx.x & 63;
  const int c0   = lane * 8;
  const int kk = row / M_, rm = row % M_;
  const int bb_ = rm / T_, t = rm % T_;
  const size_t orow = (size_t)bb_ * (K_ * T_) + (size_t)kk * T_ + t;
  const bf8 xv = *(const bf8*)&t2[(size_t)row * D_ + c0];
  float v[8];
  float s = 0.0f;
#pragma unroll
  for (int e = 0; e < 8; ++e) { v[e] = bf2f(xv[e]); s += v[e]; }
  const float mean = wave_sum(s) * (1.0f / D_);
  float s2 = 0.0f;
#pragma unroll
  for (int e = 0; e < 8; ++e) { v[e] -= mean; s2 += v[e] * v[e]; }
  const float inv = rsqrtf(wave_sum(s2) * (1.0f / D_) + EPS_);
  const float4 g0 = *(const float4*)&g[c0];
  const float4 g1 = *(const float4*)&g[c0 + 4];
  const float4 b0 = *(const float4*)&b[c0];
  const float4 b1 = *(const float4*)&b[c0 + 4];
  float4 o0, o1;
  o0.x = v[0] * inv * g0.x + b0.x;
  o0.y = v[1] * inv * g0.y + b0.y;
  o0.z = v[2] * inv * g0.z + b0.z;
  o0.w = v[3] * inv * g0.w + b0.w;
  o1.x = v[4] * inv * g1.x + b1.x;
  o1.y = v[5] * inv * g1.y + b1.y;
  o1.z = v[6] * inv * g1.z + b1.z;
  o1.w = v[7] * inv * g1.w + b1.w;
  *(float4*)&out[orow * D_ + c0]     = o0;
  *(float4*)&out[orow * D_ + c0 + 4] = o1;
}

// ---------------- MFMA banded attention, both streams
// q [2M,D] bf16 (unswizzled); KVp [M,2D] bf16 (unswizzled); out bf16 swizzled
// Loaders vectorized to 16B/lane (bf8) — 4x fewer load instructions (G13).
#define QT_  64
#define KT_  (QT_ + 2 * BAND_)   // 112 rows
#define SKQ_ 72                  // row stride (shorts) for sK/sQ/sP (144B = 9*16B aligned)
#define STV_ 136                 // row stride (shorts) for sVt
__global__ __launch_bounds__(256) void attn_mfma_k(
    const short* __restrict__ q, const short* __restrict__ KVp,
    short* __restrict__ out) {
  __shared__ short sK[KT_ * SKQ_];
  __shared__ short sQ[QT_ * SKQ_];
  __shared__ short sVt[DH_ * STV_];     // transposed: [dim][key row]
  __shared__ short sP[4][16 * SKQ_];
  const int t0 = blockIdx.x * QT_;
  const int h  = blockIdx.y;
  const int z  = blockIdx.z;            // kk*B + b
  const int b  = z % B_;
  const int tid = threadIdx.x;
  const int wave = tid >> 6, lane = tid & 63;
  const int r8 = tid >> 3;              // 0..31
  const int c8 = (tid & 7) * 8;         // 16B column offset within 64-wide head slice

  for (int r0 = 0; r0 < KT_; r0 += 32) {
    const int r = r0 + r8;
    if (r < KT_) {
      const int s = t0 - BAND_ + r;
      bf8 kv = {0,0,0,0,0,0,0,0}, vv = {0,0,0,0,0,0,0,0};
      if (s >= 0 && s < T_) {
        const size_t g = (size_t)(b * T_ + s) * (2 * D_) + h * DH_ + c8;
        kv = *(const bf8*)&KVp[g];
        vv = *(const bf8*)&KVp[g + D_];
      }
      *(bf8*)&sK[r * SKQ_ + c8] = kv;
#pragma unroll
      for (int e = 0; e < 8; ++e) sVt[(c8 + e) * STV_ + r] = vv[e];
    }
  }
#pragma unroll
  for (int r0 = 0; r0 < QT_; r0 += 32) {
    const int r = r0 + r8;
    const size_t g = (size_t)(z * T_ + t0 + r) * D_ + h * DH_ + c8;
    *(bf8*)&sQ[r * SKQ_ + c8] = *(const bf8*)&q[g];
  }
  __syncthreads();

  const int qg  = wave * 16;            // query group base (also key window base)
  const int l15 = lane & 15, quad = lane >> 4;

  // ---- S = Q16x64 @ K64x64^T  (8 MFMAs)
  bf8 qa0 = *(const bf8*)&sQ[(qg + l15) * SKQ_ + quad * 8];
  bf8 qa1 = *(const bf8*)&sQ[(qg + l15) * SKQ_ + 32 + quad * 8];
  f32x4 acc[4];
#pragma unroll
  for (int j = 0; j < 4; ++j) {
    const bf8 kb0 = *(const bf8*)&sK[(qg + j * 16 + l15) * SKQ_ + quad * 8];
    const bf8 kb1 = *(const bf8*)&sK[(qg + j * 16 + l15) * SKQ_ + 32 + quad * 8];
    f32x4 z4 = {0.f, 0.f, 0.f, 0.f};
    acc[j] = __builtin_amdgcn_mfma_f32_16x16x32_bf16(qa0, kb0, z4, 0, 0, 0);
    acc[j] = __builtin_amdgcn_mfma_f32_16x16x32_bf16(qa1, kb1, acc[j], 0, 0, 0);
  }

  // ---- banded softmax on C-layout rows (row = quad*4+reg, col = j*16+l15)
#pragma unroll
  for (int reg = 0; reg < 4; ++reg) {
    const int i = quad * 4 + reg;       // query within group
    float sc[4];
    float mx = -1e30f;
#pragma unroll
    for (int j = 0; j < 4; ++j) {
      const int c = j * 16 + l15;       // key within 64-window
      const int s = t0 + qg - BAND_ + c;
      const int rel = c - i;            // in [0,48] when inside band
      const bool valid = (rel >= 0) && (rel <= 2 * BAND_) && (s >= 0) && (s < T_);
      sc[j] = valid ? acc[j][reg] * 0.125f : -1e30f;
      mx = fmaxf(mx, sc[j]);
    }
    for (int o = 1; o < 16; o <<= 1) mx = fmaxf(mx, __shfl_xor(mx, o));
    float p[4], se = 0.0f;
#pragma unroll
    for (int j = 0; j < 4; ++j) {
      p[j] = (sc[j] > -1e29f) ? __expf(sc[j] - mx) : 0.0f;
      se += p[j];
    }
    for (int o = 1; o < 16; o <<= 1) se += __shfl_xor(se, o);
    const float inv = __builtin_amdgcn_rcpf(se);
#pragma unroll
    for (int j = 0; j < 4; ++j)
      sP[wave][i * SKQ_ + j * 16 + l15] = f2bf(p[j] * inv);
  }

  // ---- O = P16x64 @ V64x64  (8 MFMAs; V from transposed LDS)
  const bf8 pa0 = *(const bf8*)&sP[wave][l15 * SKQ_ + quad * 8];
  const bf8 pa1 = *(const bf8*)&sP[wave][l15 * SKQ_ + 32 + quad * 8];
  f32x4 oacc[4] = {};
#pragma unroll
  for (int dt = 0; dt < 4; ++dt) {
    const bf8 vb0 = *(const bf8*)&sVt[(dt * 16 + l15) * STV_ + qg + quad * 8];
    const bf8 vb1 = *(const bf8*)&sVt[(dt * 16 + l15) * STV_ + qg + 32 + quad * 8];
    oacc[dt] = __builtin_amdgcn_mfma_f32_16x16x32_bf16(pa0, vb0, oacc[dt], 0, 0, 0);
    oacc[dt] = __builtin_amdgcn_mfma_f32_16x16x32_bf16(pa1, vb1, oacc[dt], 0, 0, 0);
  }
#pragma unroll
  for (int dt = 0; dt < 4; ++dt)
#pragma unroll
    for (int reg = 0; reg < 4; ++reg) {
      const int i = quad * 4 + reg;
      const int row = t0 + qg + i;
      const int col = h * DH_ + dt * 16 + l15;
      out[(size_t)(z * T_ + row) * D_ + swz64(row, col)] = f2bf(oacc[dt][reg]);
    }
}

extern "C" void kernel_launch(void* const* d_in, const int* in_sizes, int n_in,
                              void* d_out, int out_size, void* d_ws, size_t ws_size,
                              hipStream_t stream) {
  const float* x_m    = (const float*)d_in[0];
  const float* A      = (const float*)d_in[1];
  const float* W_in   = (const float*)d_in[2];
  const float* b_in   = (const float*)d_in[3];
  const float* ln_q_g = (const float*)d_in[4];
  const float* ln_q_b = (const float*)d_in[5];
  const float* ln_kv_g= (const float*)d_in[6];
  const float* ln_kv_b= (const float*)d_in[7];
  const float* Wq     = (const float*)d_in[8];
  const float* bq     = (const float*)d_in[9];
  const float* Wk     = (const float*)d_in[10];
  const float* bk     = (const float*)d_in[11];
  const float* Wv     = (const float*)d_in[12];
  const float* bv     = (const float*)d_in[13];
  const float* Wo     = (const float*)d_in[14];
  const float* bo     = (const float*)d_in[15];
  const float* ln_f_g = (const float*)d_in[16];
  const float* ln_f_b = (const float*)d_in[17];
  const float* W1     = (const float*)d_in[18];
  const float* b1     = (const float*)d_in[19];
  const float* W2     = (const float*)d_in[20];
  const float* b2     = (const float*)d_in[21];
  const float* ln_s_g = (const float*)d_in[22];
  const float* ln_s_b = (const float*)d_in[23];
  const float* tags   = (const float*)d_in[24];
  float* out = (float*)d_out;

  const size_t MD = (size_t)M_ * D_;
  // fp32 buffers
  float* bkv = (float*)d_ws;           // [1024]
  // bf16 buffers
  short* X    = (short*)(bkv + 1024);  // [M,D]  unswizzled
  short* Xk2  = X    + MD;             // [2M,D] gated X, then y (bf16, unswizzled)
  short* LNb2 = Xk2  + 2 * MD;         // [2M,D] q-LN (swizzled), then attn out
  short* qb2  = LNb2 + 2 * MD;         // [2M,D]; first MD also = xb (x_m bf16 swz)
  short* KVpb = qb2  + 2 * MD;         // [M,2D] interleaved K|V (unswizzled)
  short* T2b  = KVpb + 2 * MD;         // [2M,D] y+h2+tag (bf16)
  short* H1b  = T2b  + 2 * MD;         // [2M,4D] swizzled
  short* WtIn = H1b + (size_t)M2_ * 4 * D_;
  short* WtQ  = WtIn + (size_t)D_ * DIN_;
  short* WtKV = WtQ  + (size_t)D_ * D_;        // [2D, D]
  short* WtO  = WtKV + (size_t)2 * D_ * D_;
  short* Wt1  = WtO  + (size_t)D_ * D_;        // [4D, D]
  short* Wt2  = Wt1  + (size_t)4 * D_ * D_;    // [D, 4D]
  short* KVb  = Wt2  + (size_t)4 * D_ * D_;    // [M,D] KV-LN (swizzled) — no alias
  short* xb   = qb2;                   // alias (used before Q GEMM)

  // ---- merged prep: x_m cast + 7 weight transposes + K/V bias concat (1 launch)
  prep_k<<<6404, 256, 0, stream>>>(x_m, xb, W_in, WtIn, Wq, WtQ, Wk, Wv, WtKV,
                                   Wo, WtO, W1, Wt1, W2, Wt2, bk, bv, bkv);

  // X = x_m @ W_in + b_in  (bf16 unswizzled out; BK=128 -> 4 K-steps)
  gemm_bt_t<128,64,4,2,128, 2><<<(D_/64) * (M_/128), 256, 0, stream>>>(
      xb, WtIn, b_in, nullptr, nullptr, X, M_, D_, DIN_, D_/64);

  // merged: KVb = LN_kv(X) (swz); Xk2 = gate(X); LNb2 = LN_q(gate(X)) (swz)
  ln_gate_k<<<(3 * M_) / 4, 256, 0, stream>>>(
      X, A, ln_kv_g, ln_kv_b, ln_q_g, ln_q_b, KVb, Xk2, LNb2);

  // dual GEMM: [KV: KVb @ WtKV -> KVpb (N=1024, 384 blocks)] +
  //            [Q:  LNb2 @ WtQ -> qb2  (N=512, 384 blocks)]  in one 768-block launch
  gemm_dual_k<<<768, 256, 0, stream>>>(
      KVb, WtKV, bkv, KVpb, 2 * D_, ((2*D_)/128) * (M_/128), (2*D_)/128,
      LNb2, WtQ, bq, qb2, D_, D_/128);

  attn_mfma_k<<<dim3(T_/QT_, H_, B_*K_), 256, 0, stream>>>(qb2, KVpb, LNb2);
  // y = attn @ Wo + bo + Xk  (bf16 in-place, bf16 res; 128x128 tile, BK=128)
  gemm_bt_t<128,128,4,4,128, 2|8><<<(D_/128) * (M2_/128), 256, 0, stream>>>(
      LNb2, WtO, bo, Xk2, nullptr, Xk2, M2_, D_, D_, D_/128);
  ln_bf_k<<<M2_/4, 256, 0, stream>>>(Xk2, ln_f_g, ln_f_b, LNb2);
  // H1 = gelu(LN @ W1 + b1)  (512-thread 256x64 FFN kernel; confirmed win R11)
  gemm_ffn_t<1|4><<<((4*D_)/64) * (M2_/256), 512, 0, stream>>>(
      LNb2, Wt1, b1, nullptr, nullptr, H1b, 4*D_, D_, (4*D_)/64);
  // T2b = h1 @ W2 + b2 + y + tag  (512-thread 256x64 FFN kernel: 384 blocks x
  // 8 waves = ~12 waves/CU vs 4 at the 128x128 config; conflict-free BK=64)
  gemm_ffn_t<8|32><<<(D_/64) * (M2_/256), 512, 0, stream>>>(
      H1b, Wt2, b2, Xk2, tags, T2b, D_, 4*D_, D_/64);
  final_ln_k<<<M2_/4, 256, 0, stream>>>(T2b, ln_s_g, ln_s_b, out);
}

// Round 13
// 281.888 us; speedup vs baseline: 1.0242x; 1.0242x over previous
//
#include <hip/hip_runtime.h>
#include <hip/hip_bf16.h>
#include <math.h>

#define B_    4
#define T_    1536
#define DIN_  512
#define D_    512
#define K_    2
#define H_    8
#define BAND_ 24
#define DH_   64
#define M_    (B_*T_)      // 6144 rows
#define M2_   (2*M_)       // both streams batched
#define ALPHA_ 6.0f
#define BETA_  0.5f
#define EPS_   1e-5f

using bf8  = __attribute__((ext_vector_type(8))) short;   // 8 bf16 (4 VGPRs)
using f32x4 = __attribute__((ext_vector_type(4))) float;  // 4 fp32 acc

__device__ __forceinline__ void async_copy16(const void* g, void* l) {
  __builtin_amdgcn_global_load_lds(
      (const __attribute__((address_space(1))) unsigned int*)g,
      (__attribute__((address_space(3))) unsigned int*)l, 16, 0, 0);
}

__device__ __forceinline__ short f2bf(float v) {
  __hip_bfloat16 h = (__hip_bfloat16)v;
  return *(short*)&h;
}
__device__ __forceinline__ float bf2f(short s) {
  union { unsigned u; float f; } c;
  c.u = ((unsigned)(unsigned short)s) << 16;
  return c.f;
}
// XOR-swizzle of 16B chunks within each 64-element column block (bank-conflict fix)
__device__ __forceinline__ int swz64(int row, int col) {
  return (col & ~63) | ((((col >> 3) ^ row) & 7) << 3) | (col & 7);
}
// tanh-form gelu, 7 VALU (2*log2e folded into polynomial), max err ~1e-3
__device__ __forceinline__ float fast_gelu(float x) {
  const float t = fmaf(0.1029504013f, x * x, 2.3021170686f);  // (a x^2 + b)*2*log2e
  const float e = __builtin_amdgcn_exp2f(x * t);              // e^{2u}
  const float r = __builtin_amdgcn_rcpf(e + 1.0f);
  return fmaf(-x, r, x);
}
// 64-lane butterfly sum
__device__ __forceinline__ float wave_sum(float s) {
#pragma unroll
  for (int o = 1; o < 64; o <<= 1) s += __shfl_xor(s, o);
  return s;
}

// ---------------- bf16 MFMA GEMM: C = A[M,Kd] @ Bt[N,Kd]^T + bias (+res) (+gelu) (+tag)
// A and Bt chunk-swizzled (per 64-element K-block). FLAGS: 1=gelu, 2=bf16 out,
// 4=swizzled out, 8=bf16 residual, 16=fp32 residual, 32=speaker tag.
// TRANSPOSED-ACC epilogue: mfma(bF, aF) => out row = l15, col = quad*4+reg.
template<int BM, int BN, int NI, int NJ, int BK, int FLAGS>
__global__ __launch_bounds__(256) void gemm_bt_t(
    const short* __restrict__ A, const short* __restrict__ Bt,
    const float* __restrict__ bias, const void* __restrict__ res,
    const float* __restrict__ tag2,
    void* __restrict__ Cout, int M, int N, int Kd, int gx) {
  constexpr int CPR  = BK / 8;          // 16B chunks per row
  constexpr int CLOG = (BK == 128) ? 4 : 3;
  __shared__ short lA[BM * BK];
  __shared__ short lB[BN * BK];
  const int gy   = gridDim.x / gx;
  const int xcd  = blockIdx.x & 7;
  const int seq  = blockIdx.x >> 3;
  const int rpx  = gy >> 3;                 // row-tiles per XCD
  const int by   = xcd * rpx + seq / gx;
  const int bx   = seq % gx;
  const int tid  = threadIdx.x;
  const int wave = tid >> 6, lane = tid & 63;
  const int block_m = by * BM, block_n = bx * BN;
  const int wm = (wave & 1) * (BM / 2), wn = (wave >> 1) * (BN / 2);
  const int l15 = lane & 15, quad = lane >> 4, l7 = lane & 7;
  f32x4 acc[NI][NJ] = {};

  for (int k0 = 0; k0 < Kd; k0 += BK) {
    __syncthreads();               // previous step's LDS reads complete
#pragma unroll
    for (int i = 0; i < (BM * CPR) / 256; ++i) {
      const int cb = wave * (BM * CPR / 4) + i * 64;
      const int c  = cb + lane;                 // chunk of 8 bf16
      async_copy16(A + (size_t)(block_m + (c >> CLOG)) * Kd + k0 + (c & (CPR - 1)) * 8,
                   &lA[cb * 8]);
    }
#pragma unroll
    for (int i = 0; i < (BN * CPR) / 256; ++i) {
      const int cb = wave * (BN * CPR / 4) + i * 64;
      const int c  = cb + lane;
      async_copy16(Bt + (size_t)(block_n + (c >> CLOG)) * Kd + k0 + (c & (CPR - 1)) * 8,
                   &lB[cb * 8]);
    }
    __syncthreads();               // barrier drains vmcnt => LDS tiles ready
#pragma unroll
    for (int ks = 0; ks < BK / 32; ++ks) {
      const int kidx = ks * 4 + quad;
      const int koff = ((kidx & ~7) | ((kidx ^ l7) & 7)) << 3;
      bf8 af[NI], bfr[NJ];
#pragma unroll
      for (int i = 0; i < NI; ++i)
        af[i] = *(const bf8*)&lA[(wm + i * 16 + l15) * BK + koff];
#pragma unroll
      for (int j = 0; j < NJ; ++j)
        bfr[j] = *(const bf8*)&lB[(wn + j * 16 + l15) * BK + koff];
#pragma unroll
      for (int i = 0; i < NI; ++i)
#pragma unroll
        for (int j = 0; j < NJ; ++j)
          acc[i][j] = __builtin_amdgcn_mfma_f32_16x16x32_bf16(bfr[j], af[i], acc[i][j], 0, 0, 0);
    }
  }

  const int half = M >> 1;
#pragma unroll
  for (int i = 0; i < NI; ++i) {
    const int row  = block_m + wm + i * 16 + l15;
    const size_t rowN = (size_t)row * N;
    const int toff = (row >= half) ? N : 0;
#pragma unroll
    for (int j = 0; j < NJ; ++j) {
      const int colb = block_n + wn + j * 16 + quad * 4;
      const float4 bb = *(const float4*)&bias[colb];
      float v0 = acc[i][j][0] + bb.x;
      float v1 = acc[i][j][1] + bb.y;
      float v2 = acc[i][j][2] + bb.z;
      float v3 = acc[i][j][3] + bb.w;
      if constexpr (FLAGS & 8) {
        const short4 rv = *(const short4*)&((const short*)res)[rowN + colb];
        v0 += bf2f(rv.x); v1 += bf2f(rv.y); v2 += bf2f(rv.z); v3 += bf2f(rv.w);
      }
      if constexpr (FLAGS & 16) {
        const float4 rv = *(const float4*)&((const float*)res)[rowN + colb];
        v0 += rv.x; v1 += rv.y; v2 += rv.z; v3 += rv.w;
      }
      if constexpr (FLAGS & 32) {
        const float4 tg = *(const float4*)&tag2[toff + colb];
        v0 += tg.x; v1 += tg.y; v2 += tg.z; v3 += tg.w;
      }
      if constexpr (FLAGS & 1) {
        v0 = fast_gelu(v0); v1 = fast_gelu(v1);
        v2 = fast_gelu(v2); v3 = fast_gelu(v3);
      }
      if constexpr (FLAGS & 2) {
        const int oc = (FLAGS & 4) ? swz64(row, colb) : colb;
        short4 o;
        o.x = f2bf(v0); o.y = f2bf(v1); o.z = f2bf(v2); o.w = f2bf(v3);
        *(short4*)&((short*)Cout)[rowN + oc] = o;
      } else {
        float4 o; o.x = v0; o.y = v1; o.z = v2; o.w = v3;
        *(float4*)&((float*)Cout)[rowN + colb] = o;
      }
    }
  }
}

// ---------------- W1 FFN GEMM: 512-thread 8-wave 256x64 tile, BK=64.
// Mechanism (CONFIRMED R11: W1 47.8 -> <42.6 us): 8 waves/block at 40KB LDS
// raises resident waves/CU 2-4x; short K (8 steps) keeps drains cheap.
// FLAGS: 1=gelu, 4=swizzled out. bf16 out.
template<int FLAGS>
__global__ __launch_bounds__(512) void gemm_ffn_t(
    const short* __restrict__ A, const short* __restrict__ Bt,
    const float* __restrict__ bias, const short* __restrict__ res,
    const float* __restrict__ tag2, short* __restrict__ Cout,
    int N, int Kd, int gx) {
  __shared__ short lA[256 * 64];
  __shared__ short lB[64 * 64];
  const int gy   = gridDim.x / gx;
  const int xcd  = blockIdx.x & 7;
  const int seq  = blockIdx.x >> 3;
  const int rpx  = gy >> 3;
  const int by   = xcd * rpx + seq / gx;
  const int bx   = seq % gx;
  const int tid  = threadIdx.x;
  const int wave = tid >> 6, lane = tid & 63;
  const int block_m = by * 256, block_n = bx * 64;
  const int wm = (wave & 3) * 64, wn = (wave >> 2) * 32;
  const int l15 = lane & 15, quad = lane >> 4, l7 = lane & 7;
  f32x4 acc[4][2] = {};

  for (int k0 = 0; k0 < Kd; k0 += 64) {
    __syncthreads();
#pragma unroll
    for (int i = 0; i < 4; ++i) {
      const int cb = wave * 256 + i * 64;
      const int c  = cb + lane;
      async_copy16(A + (size_t)(block_m + (c >> 3)) * Kd + k0 + (c & 7) * 8,
                   &lA[cb * 8]);
    }
    {
      const int cb = wave * 64;
      const int c  = cb + lane;
      async_copy16(Bt + (size_t)(block_n + (c >> 3)) * Kd + k0 + (c & 7) * 8,
                   &lB[cb * 8]);
    }
    __syncthreads();
#pragma unroll
    for (int ks = 0; ks < 2; ++ks) {
      const int koff = (((ks * 4 + quad) ^ l7) << 3);
      bf8 af[4], bfr[2];
#pragma unroll
      for (int i = 0; i < 4; ++i)
        af[i] = *(const bf8*)&lA[(wm + i * 16 + l15) * 64 + koff];
#pragma unroll
      for (int j = 0; j < 2; ++j)
        bfr[j] = *(const bf8*)&lB[(wn + j * 16 + l15) * 64 + koff];
#pragma unroll
      for (int i = 0; i < 4; ++i)
#pragma unroll
        for (int j = 0; j < 2; ++j)
          acc[i][j] = __builtin_amdgcn_mfma_f32_16x16x32_bf16(bfr[j], af[i], acc[i][j], 0, 0, 0);
    }
  }

#pragma unroll
  for (int i = 0; i < 4; ++i) {
    const int row  = block_m + wm + i * 16 + l15;
    const size_t rowN = (size_t)row * N;
    const int toff = (row >= M_) ? N : 0;
#pragma unroll
    for (int j = 0; j < 2; ++j) {
      const int colb = block_n + wn + j * 16 + quad * 4;
      const float4 bb = *(const float4*)&bias[colb];
      float v0 = acc[i][j][0] + bb.x;
      float v1 = acc[i][j][1] + bb.y;
      float v2 = acc[i][j][2] + bb.z;
      float v3 = acc[i][j][3] + bb.w;
      if constexpr (FLAGS & 8) {
        const short4 rv = *(const short4*)&res[rowN + colb];
        v0 += bf2f(rv.x); v1 += bf2f(rv.y); v2 += bf2f(rv.z); v3 += bf2f(rv.w);
      }
      if constexpr (FLAGS & 32) {
        const float4 tg = *(const float4*)&tag2[toff + colb];
        v0 += tg.x; v1 += tg.y; v2 += tg.z; v3 += tg.w;
      }
      if constexpr (FLAGS & 1) {
        v0 = fast_gelu(v0); v1 = fast_gelu(v1);
        v2 = fast_gelu(v2); v3 = fast_gelu(v3);
      }
      const int oc = (FLAGS & 4) ? swz64(row, colb) : colb;
      short4 o;
      o.x = f2bf(v0); o.y = f2bf(v1); o.z = f2bf(v2); o.w = f2bf(v3);
      *(short4*)&Cout[rowN + oc] = o;
    }
  }
}

// ---------------- W2 FFN GEMM: 512-thread 8-wave 128x128 tile, BK=128.
// Combines BOTH confirmed mechanisms: 16 drains (= R11's best W2 config,
// long-K needs few drains) AND 8 waves/block @64KB LDS -> 2 blocks/CU = 16
// waves/CU (R11's 256-thread version was capped at 13% occupancy / ~4 waves;
// the 512-thread split halves per-thread acc VGPRs 64->32). Per-wave
// compute:stage ratio unchanged (32 MFMA / 8 chunks per K-step).
// FLAGS: 8=bf16 residual, 32=speaker tag. bf16 out, unswizzled.
template<int FLAGS>
__global__ __launch_bounds__(512) void gemm_ffn2_t(
    const short* __restrict__ A, const short* __restrict__ Bt,
    const float* __restrict__ bias, const short* __restrict__ res,
    const float* __restrict__ tag2, short* __restrict__ Cout,
    int N, int Kd, int gx) {
  __shared__ short lA[128 * 128];
  __shared__ short lB[128 * 128];
  const int gy   = gridDim.x / gx;
  const int xcd  = blockIdx.x & 7;
  const int seq  = blockIdx.x >> 3;
  const int rpx  = gy >> 3;
  const int by   = xcd * rpx + seq / gx;
  const int bx   = seq % gx;
  const int tid  = threadIdx.x;
  const int wave = tid >> 6, lane = tid & 63;
  const int block_m = by * 128, block_n = bx * 128;
  const int wm = (wave & 1) * 64, wn = (wave >> 1) * 32;
  const int l15 = lane & 15, quad = lane >> 4, l7 = lane & 7;
  f32x4 acc[4][2] = {};

  for (int k0 = 0; k0 < Kd; k0 += 128) {
    __syncthreads();
#pragma unroll
    for (int i = 0; i < 4; ++i) {       // A: 128 rows x 16 chunks = 2048 / 512t
      const int cb = wave * 256 + i * 64;
      const int c  = cb + lane;
      async_copy16(A + (size_t)(block_m + (c >> 4)) * Kd + k0 + (c & 15) * 8,
                   &lA[cb * 8]);
    }
#pragma unroll
    for (int i = 0; i < 4; ++i) {       // B: same shape
      const int cb = wave * 256 + i * 64;
      const int c  = cb + lane;
      async_copy16(Bt + (size_t)(block_n + (c >> 4)) * Kd + k0 + (c & 15) * 8,
                   &lB[cb * 8]);
    }
    __syncthreads();
#pragma unroll
    for (int ks = 0; ks < 4; ++ks) {
      const int kidx = ks * 4 + quad;
      const int koff = ((kidx & ~7) | ((kidx ^ l7) & 7)) << 3;
      bf8 af[4], bfr[2];
#pragma unroll
      for (int i = 0; i < 4; ++i)
        af[i] = *(const bf8*)&lA[(wm + i * 16 + l15) * 128 + koff];
#pragma unroll
      for (int j = 0; j < 2; ++j)
        bfr[j] = *(const bf8*)&lB[(wn + j * 16 + l15) * 128 + koff];
#pragma unroll
      for (int i = 0; i < 4; ++i)
#pragma unroll
        for (int j = 0; j < 2; ++j)
          acc[i][j] = __builtin_amdgcn_mfma_f32_16x16x32_bf16(bfr[j], af[i], acc[i][j], 0, 0, 0);
    }
  }

#pragma unroll
  for (int i = 0; i < 4; ++i) {
    const int row  = block_m + wm + i * 16 + l15;
    const size_t rowN = (size_t)row * N;
    const int toff = (row >= M_) ? N : 0;
#pragma unroll
    for (int j = 0; j < 2; ++j) {
      const int colb = block_n + wn + j * 16 + quad * 4;
      const float4 bb = *(const float4*)&bias[colb];
      float v0 = acc[i][j][0] + bb.x;
      float v1 = acc[i][j][1] + bb.y;
      float v2 = acc[i][j][2] + bb.z;
      float v3 = acc[i][j][3] + bb.w;
      if constexpr (FLAGS & 8) {
        const short4 rv = *(const short4*)&res[rowN + colb];
        v0 += bf2f(rv.x); v1 += bf2f(rv.y); v2 += bf2f(rv.z); v3 += bf2f(rv.w);
      }
      if constexpr (FLAGS & 32) {
        const float4 tg = *(const float4*)&tag2[toff + colb];
        v0 += tg.x; v1 += tg.y; v2 += tg.z; v3 += tg.w;
      }
      short4 o;
      o.x = f2bf(v0); o.y = f2bf(v1); o.z = f2bf(v2); o.w = f2bf(v3);
      *(short4*)&Cout[rowN + colb] = o;
    }
  }
}

// ---- shared 128x128 FLAGS=2 core (bf16 out, bias only), BK=64 single-buffer
// (round-3 proven; used by the dual KV/Q kernel)
__device__ __forceinline__ void gemm128_core(
    const short* __restrict__ A, const short* __restrict__ Bt,
    const float* __restrict__ bias, short* __restrict__ Cout,
    int N, int Kd, int bid, int gx, int gy, short* lA, short* lB) {
  const int xcd  = bid & 7;
  const int seq  = bid >> 3;
  const int rpx  = gy >> 3;
  const int by   = xcd * rpx + seq / gx;
  const int bx   = seq % gx;
  const int tid  = threadIdx.x;
  const int wave = tid >> 6, lane = tid & 63;
  const int block_m = by * 128, block_n = bx * 128;
  const int wm = (wave & 1) * 64, wn = (wave >> 1) * 64;
  const int l15 = lane & 15, quad = lane >> 4, l7 = lane & 7;
  f32x4 acc[4][4] = {};

  for (int k0 = 0; k0 < Kd; k0 += 64) {
    __syncthreads();
#pragma unroll
    for (int i = 0; i < 4; ++i) {
      const int cb = wave * 256 + i * 64;
      const int c  = cb + lane;
      async_copy16(A + (size_t)(block_m + (c >> 3)) * Kd + k0 + (c & 7) * 8,
                   &lA[cb * 8]);
    }
#pragma unroll
    for (int i = 0; i < 4; ++i) {
      const int cb = wave * 256 + i * 64;
      const int c  = cb + lane;
      async_copy16(Bt + (size_t)(block_n + (c >> 3)) * Kd + k0 + (c & 7) * 8,
                   &lB[cb * 8]);
    }
    __syncthreads();
#pragma unroll
    for (int ks = 0; ks < 2; ++ks) {
      bf8 af[4], bfr[4];
#pragma unroll
      for (int i = 0; i < 4; ++i)
        af[i] = *(const bf8*)&lA[(wm + i * 16 + l15) * 64 + (((ks * 4 + quad) ^ l7) << 3)];
#pragma unroll
      for (int j = 0; j < 4; ++j)
        bfr[j] = *(const bf8*)&lB[(wn + j * 16 + l15) * 64 + (((ks * 4 + quad) ^ l7) << 3)];
#pragma unroll
      for (int i = 0; i < 4; ++i)
#pragma unroll
        for (int j = 0; j < 4; ++j)
          acc[i][j] = __builtin_amdgcn_mfma_f32_16x16x32_bf16(bfr[j], af[i], acc[i][j], 0, 0, 0);
    }
  }

#pragma unroll
  for (int i = 0; i < 4; ++i) {
    const int row  = block_m + wm + i * 16 + l15;
    const size_t rowN = (size_t)row * N;
#pragma unroll
    for (int j = 0; j < 4; ++j) {
      const int colb = block_n + wn + j * 16 + quad * 4;
      const float4 bb = *(const float4*)&bias[colb];
      short4 o;
      o.x = f2bf(acc[i][j][0] + bb.x);
      o.y = f2bf(acc[i][j][1] + bb.y);
      o.z = f2bf(acc[i][j][2] + bb.z);
      o.w = f2bf(acc[i][j][3] + bb.w);
      *(short4*)&Cout[rowN + colb] = o;
    }
  }
}

// ---- dual GEMM: first nb0 blocks = GEMM0 (KV), rest = GEMM1 (Q). One launch,
// perfect 3-blocks/CU balance instead of two 1.5-blocks/CU launches with tails.
__global__ __launch_bounds__(256) void gemm_dual_k(
    const short* __restrict__ A0, const short* __restrict__ Bt0,
    const float* __restrict__ bias0, short* __restrict__ C0, int N0, int nb0, int gx0,
    const short* __restrict__ A1, const short* __restrict__ Bt1,
    const float* __restrict__ bias1, short* __restrict__ C1, int N1, int gx1) {
  __shared__ short lA[128 * 64];
  __shared__ short lB[128 * 64];
  const int bid = blockIdx.x;
  if (bid < nb0) {
    gemm128_core(A0, Bt0, bias0, C0, N0, D_, bid, gx0, nb0 / gx0, lA, lB);
  } else {
    const int b1 = bid - nb0;
    const int nb1 = gridDim.x - nb0;
    gemm128_core(A1, Bt1, bias1, C1, N1, D_, b1, gx1, nb1 / gx1, lA, lB);
  }
}

// ---------------- merged prep: x_m cast (swizzled) + 7 weight transposes + bias concat
__device__ __forceinline__ void tconv_tile(const float* __restrict__ W,
                                           short* __restrict__ Wt, int K, int N,
                                           int bx, int by, int tid, float (*s)[33]) {
  const int tx = tid & 31, ty = tid >> 5;
  const int k0 = by * 32, n0 = bx * 32;
#pragma unroll
  for (int r = 0; r < 4; ++r)
    s[ty * 4 + r][tx] = W[(size_t)(k0 + ty * 4 + r) * N + n0 + tx];
  __syncthreads();
#pragma unroll
  for (int r = 0; r < 4; ++r) {
    const int n = n0 + ty * 4 + r;
    Wt[(size_t)n * K + swz64(n, k0 + tx)] = f2bf(s[tx][ty * 4 + r]);
  }
}

__global__ __launch_bounds__(256) void prep_k(
    const float* __restrict__ x_m, short* __restrict__ xb,
    const float* __restrict__ W_in, short* __restrict__ WtIn,
    const float* __restrict__ Wq,  short* __restrict__ WtQ,
    const float* __restrict__ Wk,  const float* __restrict__ Wv,
    short* __restrict__ WtKV,
    const float* __restrict__ Wo,  short* __restrict__ WtO,
    const float* __restrict__ W1,  short* __restrict__ Wt1,
    const float* __restrict__ W2,  short* __restrict__ Wt2,
    const float* __restrict__ bk,  const float* __restrict__ bv,
    float* __restrict__ bkv) {
  __shared__ float s[32][33];
  const int blk = blockIdx.x, tid = threadIdx.x;
  if (blk < 3072) {                       // x_m -> bf16 swizzled (float4 per thread)
    const int e = (blk * 256 + tid) * 4;
    const int row = e >> 9, col = e & 511;
    const float4 v = *(const float4*)&x_m[e];
    short4 o;
    o.x = f2bf(v.x); o.y = f2bf(v.y); o.z = f2bf(v.z); o.w = f2bf(v.w);
    *(short4*)&xb[((size_t)row << 9) | swz64(row, col)] = o;
  } else if (blk < 3328) {                // W_in [512,512]
    const int t = blk - 3072; tconv_tile(W_in, WtIn, DIN_, D_, t & 15, t >> 4, tid, s);
  } else if (blk < 3584) {                // Wq
    const int t = blk - 3328; tconv_tile(Wq, WtQ, D_, D_, t & 15, t >> 4, tid, s);
  } else if (blk < 3840) {                // Wk -> WtKV[0:512]
    const int t = blk - 3584; tconv_tile(Wk, WtKV, D_, D_, t & 15, t >> 4, tid, s);
  } else if (blk < 4096) {                // Wv -> WtKV[512:1024]
    const int t = blk - 3840; tconv_tile(Wv, WtKV + (size_t)D_ * D_, D_, D_, t & 15, t >> 4, tid, s);
  } else if (blk < 4352) {                // Wo
    const int t = blk - 4096; tconv_tile(Wo, WtO, D_, D_, t & 15, t >> 4, tid, s);
  } else if (blk < 5376) {                // W1 [512,2048]: gx=64
    const int t = blk - 4352; tconv_tile(W1, Wt1, D_, 4 * D_, t & 63, t >> 6, tid, s);
  } else if (blk < 6400) {                // W2 [2048,512]: gx=16
    const int t = blk - 5376; tconv_tile(W2, Wt2, 4 * D_, D_, t & 15, t >> 4, tid, s);
  } else {                                // bias concat (4 blocks)
    const int i = (blk - 6400) * 256 + tid;
    bkv[i] = (i < D_) ? bk[i] : bv[i - D_];
  }
}

// ---------------- LayerNorm, bf16 in: out(bf16, swizzled) = LN(in) * g + b
// one 64-lane wave per row (4 rows/block), bf8 loads, shfl reduce, no barriers
__global__ __launch_bounds__(256) void ln_bf_k(const short* __restrict__ in,
                                               const float* __restrict__ g,
                                               const float* __restrict__ b,
                                               short* __restrict__ out) {
  const int row  = blockIdx.x * 4 + (threadIdx.x >> 6);
  const int lane = threadIdx.x & 63;
  const int c0   = lane * 8;
  const bf8 xv = *(const bf8*)&in[(size_t)row * D_ + c0];
  float v[8];
  float s = 0.0f;
#pragma unroll
  for (int e = 0; e < 8; ++e) { v[e] = bf2f(xv[e]); s += v[e]; }
  const float mean = wave_sum(s) * (1.0f / D_);
  float s2 = 0.0f;
#pragma unroll
  for (int e = 0; e < 8; ++e) { v[e] -= mean; s2 += v[e] * v[e]; }
  const float inv = rsqrtf(wave_sum(s2) * (1.0f / D_) + EPS_);
  const float4 g0 = *(const float4*)&g[c0];
  const float4 g1 = *(const float4*)&g[c0 + 4];
  const float4 b0 = *(const float4*)&b[c0];
  const float4 b1 = *(const float4*)&b[c0 + 4];
  bf8 o;
  o[0] = f2bf(v[0] * inv * g0.x + b0.x);
  o[1] = f2bf(v[1] * inv * g0.y + b0.y);
  o[2] = f2bf(v[2] * inv * g0.z + b0.z);
  o[3] = f2bf(v[3] * inv * g0.w + b0.w);
  o[4] = f2bf(v[4] * inv * g1.x + b1.x);
  o[5] = f2bf(v[5] * inv * g1.y + b1.y);
  o[6] = f2bf(v[6] * inv * g1.z + b1.z);
  o[7] = f2bf(v[7] * inv * g1.w + b1.w);
  *(bf8*)&out[(size_t)row * D_ + swz64(row, c0)] = o;
}

// ---------------- merged KV-LN + gate/Q-LN: rows [0,M) = ln_kv(X) -> KVb (swizzled);
// rows [M,3M) = gate+ln_q: Xk (bf16 unswz) + LNq (swizzled). One launch, no tail.
__global__ __launch_bounds__(256) void ln_gate_k(
    const short* __restrict__ X, const float* __restrict__ Ain,
    const float* __restrict__ gkv, const float* __restrict__ bkvp,
    const float* __restrict__ gq, const float* __restrict__ bqp,
    short* __restrict__ KVb, short* __restrict__ Xk, short* __restrict__ LNq) {
  const int row  = blockIdx.x * 4 + (threadIdx.x >> 6);
  const int lane = threadIdx.x & 63;
  const int c0   = lane * 8;
  float v[8];
  float s = 0.0f;
  if (row < M_) {
    const bf8 xv = *(const bf8*)&X[(size_t)row * D_ + c0];
#pragma unroll
    for (int e = 0; e < 8; ++e) { v[e] = bf2f(xv[e]); s += v[e]; }
    const float mean = wave_sum(s) * (1.0f / D_);
    float s2 = 0.0f;
#pragma unroll
    for (int e = 0; e < 8; ++e) { v[e] -= mean; s2 += v[e] * v[e]; }
    const float inv = rsqrtf(wave_sum(s2) * (1.0f / D_) + EPS_);
    const float4 g0 = *(const float4*)&gkv[c0];
    const float4 g1 = *(const float4*)&gkv[c0 + 4];
    const float4 b0 = *(const float4*)&bkvp[c0];
    const float4 b1 = *(const float4*)&bkvp[c0 + 4];
    bf8 o;
    o[0] = f2bf(v[0] * inv * g0.x + b0.x);
    o[1] = f2bf(v[1] * inv * g0.y + b0.y);
    o[2] = f2bf(v[2] * inv * g0.z + b0.z);
    o[3] = f2bf(v[3] * inv * g0.w + b0.w);
    o[4] = f2bf(v[4] * inv * g1.x + b1.x);
    o[5] = f2bf(v[5] * inv * g1.y + b1.y);
    o[6] = f2bf(v[6] * inv * g1.z + b1.z);
    o[7] = f2bf(v[7] * inv * g1.w + b1.w);
    *(bf8*)&KVb[(size_t)row * D_ + swz64(row, c0)] = o;
  } else {
    const int r2 = row - M_;            // [0, 2M)
    const int kk = r2 / M_, rm = r2 % M_;
    const float a = Ain[(size_t)rm * K_ + kk];
    const float w = __builtin_amdgcn_rcpf(1.0f + __expf(-ALPHA_ * (a - BETA_)));
    const bf8 xv = *(const bf8*)&X[(size_t)rm * D_ + c0];
    bf8 xo;
#pragma unroll
    for (int e = 0; e < 8; ++e) {
      v[e] = bf2f(xv[e]) * w;
      xo[e] = f2bf(v[e]);
      s += v[e];
    }
    *(bf8*)&Xk[(size_t)r2 * D_ + c0] = xo;
    const float mean = wave_sum(s) * (1.0f / D_);
    float s2 = 0.0f;
#pragma unroll
    for (int e = 0; e < 8; ++e) { v[e] -= mean; s2 += v[e] * v[e]; }
    const float inv = rsqrtf(wave_sum(s2) * (1.0f / D_) + EPS_);
    const float4 g0 = *(const float4*)&gq[c0];
    const float4 g1 = *(const float4*)&gq[c0 + 4];
    const float4 b0 = *(const float4*)&bqp[c0];
    const float4 b1 = *(const float4*)&bqp[c0 + 4];
    bf8 o;
    o[0] = f2bf(v[0] * inv * g0.x + b0.x);
    o[1] = f2bf(v[1] * inv * g0.y + b0.y);
    o[2] = f2bf(v[2] * inv * g0.z + b0.z);
    o[3] = f2bf(v[3] * inv * g0.w + b0.w);
    o[4] = f2bf(v[4] * inv * g1.x + b1.x);
    o[5] = f2bf(v[5] * inv * g1.y + b1.y);
    o[6] = f2bf(v[6] * inv * g1.z + b1.z);
    o[7] = f2bf(v[7] * inv * g1.w + b1.w);
    *(bf8*)&LNq[(size_t)r2 * D_ + swz64(r2, c0)] = o;
  }
}

// ---------------- final LN: in = T2b (y+h2+tag, bf16); scatter to concat layout (fp32)
__global__ __launch_bounds__(256) void final_ln_k(
    const short* __restrict__ t2, const float* __restrict__ g,
    const float* __restrict__ b, float* __restrict__ out) {
  const int row  = blockIdx.x * 4 + (threadIdx.x >> 6);
  const int lane = threadIdx.x & 63;
  const int c0   = lane * 8;
  const int kk = row / M_, rm = row % M_;
  const int bb_ = rm / T_, t = rm % T_;
  const size_t orow = (size_t)bb_ * (K_ * T_) + (size_t)kk * T_ + t;
  const bf8 xv = *(const bf8*)&t2[(size_t)row * D_ + c0];
  float v[8];
  float s = 0.0f;
#pragma unroll
  for (int e = 0; e < 8; ++e) { v[e] = bf2f(xv[e]); s += v[e]; }
  const float mean = wave_sum(s) * (1.0f / D_);
  float s2 = 0.0f;
#pragma unroll
  for (int e = 0; e < 8; ++e) { v[e] -= mean; s2 += v[e] * v[e]; }
  const float inv = rsqrtf(wave_sum(s2) * (1.0f / D_) + EPS_);
  const float4 g0 = *(const float4*)&g[c0];
  const float4 g1 = *(const float4*)&g[c0 + 4];
  const float4 b0 = *(const float4*)&b[c0];
  const float4 b1 = *(const float4*)&b[c0 + 4];
  float4 o0, o1;
  o0.x = v[0] * inv * g0.x + b0.x;
  o0.y = v[1] * inv * g0.y + b0.y;
  o0.z = v[2] * inv * g0.z + b0.z;
  o0.w = v[3] * inv * g0.w + b0.w;
  o1.x = v[4] * inv * g1.x + b1.x;
  o1.y = v[5] * inv * g1.y + b1.y;
  o1.z = v[6] * inv * g1.z + b1.z;
  o1.w = v[7] * inv * g1.w + b1.w;
  *(float4*)&out[orow * D_ + c0]     = o0;
  *(float4*)&out[orow * D_ + c0 + 4] = o1;
}

// ---------------- MFMA banded attention, both streams
// q [2M,D] bf16 (unswizzled); KVp [M,2D] bf16 (unswizzled); out bf16 swizzled
// Loaders vectorized to 16B/lane (bf8) — 4x fewer load instructions (G13).
#define QT_  64
#define KT_  (QT_ + 2 * BAND_)   // 112 rows
#define SKQ_ 72                  // row stride (shorts) for sK/sQ/sP (144B = 9*16B aligned)
#define STV_ 136                 // row stride (shorts) for sVt
__global__ __launch_bounds__(256) void attn_mfma_k(
    const short* __restrict__ q, const short* __restrict__ KVp,
    short* __restrict__ out) {
  __shared__ short sK[KT_ * SKQ_];
  __shared__ short sQ[QT_ * SKQ_];
  __shared__ short sVt[DH_ * STV_];     // transposed: [dim][key row]
  __shared__ short sP[4][16 * SKQ_];
  const int t0 = blockIdx.x * QT_;
  const int h  = blockIdx.y;
  const int z  = blockIdx.z;            // kk*B + b
  const int b  = z % B_;
  const int tid = threadIdx.x;
  const int wave = tid >> 6, lane = tid & 63;
  const int r8 = tid >> 3;              // 0..31
  const int c8 = (tid & 7) * 8;         // 16B column offset within 64-wide head slice

  for (int r0 = 0; r0 < KT_; r0 += 32) {
    const int r = r0 + r8;
    if (r < KT_) {
      const int s = t0 - BAND_ + r;
      bf8 kv = {0,0,0,0,0,0,0,0}, vv = {0,0,0,0,0,0,0,0};
      if (s >= 0 && s < T_) {
        const size_t g = (size_t)(b * T_ + s) * (2 * D_) + h * DH_ + c8;
        kv = *(const bf8*)&KVp[g];
        vv = *(const bf8*)&KVp[g + D_];
      }
      *(bf8*)&sK[r * SKQ_ + c8] = kv;
#pragma unroll
      for (int e = 0; e < 8; ++e) sVt[(c8 + e) * STV_ + r] = vv[e];
    }
  }
#pragma unroll
  for (int r0 = 0; r0 < QT_; r0 += 32) {
    const int r = r0 + r8;
    const size_t g = (size_t)(z * T_ + t0 + r) * D_ + h * DH_ + c8;
    *(bf8*)&sQ[r * SKQ_ + c8] = *(const bf8*)&q[g];
  }
  __syncthreads();

  const int qg  = wave * 16;            // query group base (also key window base)
  const int l15 = lane & 15, quad = lane >> 4;

  // ---- S = Q16x64 @ K64x64^T  (8 MFMAs)
  bf8 qa0 = *(const bf8*)&sQ[(qg + l15) * SKQ_ + quad * 8];
  bf8 qa1 = *(const bf8*)&sQ[(qg + l15) * SKQ_ + 32 + quad * 8];
  f32x4 acc[4];
#pragma unroll
  for (int j = 0; j < 4; ++j) {
    const bf8 kb0 = *(const bf8*)&sK[(qg + j * 16 + l15) * SKQ_ + quad * 8];
    const bf8 kb1 = *(const bf8*)&sK[(qg + j * 16 + l15) * SKQ_ + 32 + quad * 8];
    f32x4 z4 = {0.f, 0.f, 0.f, 0.f};
    acc[j] = __builtin_amdgcn_mfma_f32_16x16x32_bf16(qa0, kb0, z4, 0, 0, 0);
    acc[j] = __builtin_amdgcn_mfma_f32_16x16x32_bf16(qa1, kb1, acc[j], 0, 0, 0);
  }

  // ---- banded softmax on C-layout rows (row = quad*4+reg, col = j*16+l15)
#pragma unroll
  for (int reg = 0; reg < 4; ++reg) {
    const int i = quad * 4 + reg;       // query within group
    float sc[4];
    float mx = -1e30f;
#pragma unroll
    for (int j = 0; j < 4; ++j) {
      const int c = j * 16 + l15;       // key within 64-window
      const int s = t0 + qg - BAND_ + c;
      const int rel = c - i;            // in [0,48] when inside band
      const bool valid = (rel >= 0) && (rel <= 2 * BAND_) && (s >= 0) && (s < T_);
      sc[j] = valid ? acc[j][reg] * 0.125f : -1e30f;
      mx = fmaxf(mx, sc[j]);
    }
    for (int o = 1; o < 16; o <<= 1) mx = fmaxf(mx, __shfl_xor(mx, o));
    float p[4], se = 0.0f;
#pragma unroll
    for (int j = 0; j < 4; ++j) {
      p[j] = (sc[j] > -1e29f) ? __expf(sc[j] - mx) : 0.0f;
      se += p[j];
    }
    for (int o = 1; o < 16; o <<= 1) se += __shfl_xor(se, o);
    const float inv = __builtin_amdgcn_rcpf(se);
#pragma unroll
    for (int j = 0; j < 4; ++j)
      sP[wave][i * SKQ_ + j * 16 + l15] = f2bf(p[j] * inv);
  }

  // ---- O = P16x64 @ V64x64  (8 MFMAs; V from transposed LDS)
  const bf8 pa0 = *(const bf8*)&sP[wave][l15 * SKQ_ + quad * 8];
  const bf8 pa1 = *(const bf8*)&sP[wave][l15 * SKQ_ + 32 + quad * 8];
  f32x4 oacc[4] = {};
#pragma unroll
  for (int dt = 0; dt < 4; ++dt) {
    const bf8 vb0 = *(const bf8*)&sVt[(dt * 16 + l15) * STV_ + qg + quad * 8];
    const bf8 vb1 = *(const bf8*)&sVt[(dt * 16 + l15) * STV_ + qg + 32 + quad * 8];
    oacc[dt] = __builtin_amdgcn_mfma_f32_16x16x32_bf16(pa0, vb0, oacc[dt], 0, 0, 0);
    oacc[dt] = __builtin_amdgcn_mfma_f32_16x16x32_bf16(pa1, vb1, oacc[dt], 0, 0, 0);
  }
#pragma unroll
  for (int dt = 0; dt < 4; ++dt)
#pragma unroll
    for (int reg = 0; reg < 4; ++reg) {
      const int i = quad * 4 + reg;
      const int row = t0 + qg + i;
      const int col = h * DH_ + dt * 16 + l15;
      out[(size_t)(z * T_ + row) * D_ + swz64(row, col)] = f2bf(oacc[dt][reg]);
    }
}

extern "C" void kernel_launch(void* const* d_in, const int* in_sizes, int n_in,
                              void* d_out, int out_size, void* d_ws, size_t ws_size,
                              hipStream_t stream) {
  const float* x_m    = (const float*)d_in[0];
  const float* A      = (const float*)d_in[1];
  const float* W_in   = (const float*)d_in[2];
  const float* b_in   = (const float*)d_in[3];
  const float* ln_q_g = (const float*)d_in[4];
  const float* ln_q_b = (const float*)d_in[5];
  const float* ln_kv_g= (const float*)d_in[6];
  const float* ln_kv_b= (const float*)d_in[7];
  const float* Wq     = (const float*)d_in[8];
  const float* bq     = (const float*)d_in[9];
  const float* Wk     = (const float*)d_in[10];
  const float* bk     = (const float*)d_in[11];
  const float* Wv     = (const float*)d_in[12];
  const float* bv     = (const float*)d_in[13];
  const float* Wo     = (const float*)d_in[14];
  const float* bo     = (const float*)d_in[15];
  const float* ln_f_g = (const float*)d_in[16];
  const float* ln_f_b = (const float*)d_in[17];
  const float* W1     = (const float*)d_in[18];
  const float* b1     = (const float*)d_in[19];
  const float* W2     = (const float*)d_in[20];
  const float* b2     = (const float*)d_in[21];
  const float* ln_s_g = (const float*)d_in[22];
  const float* ln_s_b = (const float*)d_in[23];
  const float* tags   = (const float*)d_in[24];
  float* out = (float*)d_out;

  const size_t MD = (size_t)M_ * D_;
  // fp32 buffers
  float* bkv = (float*)d_ws;           // [1024]
  // bf16 buffers
  short* X    = (short*)(bkv + 1024);  // [M,D]  unswizzled
  short* Xk2  = X    + MD;             // [2M,D] gated X, then y (bf16, unswizzled)
  short* LNb2 = Xk2  + 2 * MD;         // [2M,D] q-LN (swizzled), then attn out
  short* qb2  = LNb2 + 2 * MD;         // [2M,D]; first MD also = xb (x_m bf16 swz)
  short* KVpb = qb2  + 2 * MD;         // [M,2D] interleaved K|V (unswizzled)
  short* T2b  = KVpb + 2 * MD;         // [2M,D] y+h2+tag (bf16)
  short* H1b  = T2b  + 2 * MD;         // [2M,4D] swizzled
  short* WtIn = H1b + (size_t)M2_ * 4 * D_;
  short* WtQ  = WtIn + (size_t)D_ * DIN_;
  short* WtKV = WtQ  + (size_t)D_ * D_;        // [2D, D]
  short* WtO  = WtKV + (size_t)2 * D_ * D_;
  short* Wt1  = WtO  + (size_t)D_ * D_;        // [4D, D]
  short* Wt2  = Wt1  + (size_t)4 * D_ * D_;    // [D, 4D]
  short* KVb  = Wt2  + (size_t)4 * D_ * D_;    // [M,D] KV-LN (swizzled) — no alias
  short* xb   = qb2;                   // alias (used before Q GEMM)

  // ---- merged prep: x_m cast + 7 weight transposes + K/V bias concat (1 launch)
  prep_k<<<6404, 256, 0, stream>>>(x_m, xb, W_in, WtIn, Wq, WtQ, Wk, Wv, WtKV,
                                   Wo, WtO, W1, Wt1, W2, Wt2, bk, bv, bkv);

  // X = x_m @ W_in + b_in  (bf16 unswizzled out; BK=128 -> 4 K-steps)
  gemm_bt_t<128,64,4,2,128, 2><<<(D_/64) * (M_/128), 256, 0, stream>>>(
      xb, WtIn, b_in, nullptr, nullptr, X, M_, D_, DIN_, D_/64);

  // merged: KVb = LN_kv(X) (swz); Xk2 = gate(X); LNb2 = LN_q(gate(X)) (swz)
  ln_gate_k<<<(3 * M_) / 4, 256, 0, stream>>>(
      X, A, ln_kv_g, ln_kv_b, ln_q_g, ln_q_b, KVb, Xk2, LNb2);

  // dual GEMM: [KV: KVb @ WtKV -> KVpb (N=1024, 384 blocks)] +
  //            [Q:  LNb2 @ WtQ -> qb2  (N=512, 384 blocks)]  in one 768-block launch
  gemm_dual_k<<<768, 256, 0, stream>>>(
      KVb, WtKV, bkv, KVpb, 2 * D_, ((2*D_)/128) * (M_/128), (2*D_)/128,
      LNb2, WtQ, bq, qb2, D_, D_/128);

  attn_mfma_k<<<dim3(T_/QT_, H_, B_*K_), 256, 0, stream>>>(qb2, KVpb, LNb2);
  // y = attn @ Wo + bo + Xk  (bf16 in-place, bf16 res; 128x128 tile, BK=128)
  gemm_bt_t<128,128,4,4,128, 2|8><<<(D_/128) * (M2_/128), 256, 0, stream>>>(
      LNb2, WtO, bo, Xk2, nullptr, Xk2, M2_, D_, D_, D_/128);
  ln_bf_k<<<M2_/4, 256, 0, stream>>>(Xk2, ln_f_g, ln_f_b, LNb2);
  // H1 = gelu(LN @ W1 + b1)  (512-thread 256x64 FFN kernel; confirmed win R11)
  gemm_ffn_t<1|4><<<((4*D_)/64) * (M2_/256), 512, 0, stream>>>(
      LNb2, Wt1, b1, nullptr, nullptr, H1b, 4*D_, D_, (4*D_)/64);
  // T2b = h1 @ W2 + b2 + y + tag  (512-thread 128x128 BK=128: 16 drains like
  // R11's best W2 config + 16 waves/CU vs its 4)
  gemm_ffn2_t<8|32><<<(D_/128) * (M2_/128), 512, 0, stream>>>(
      H1b, Wt2, b2, Xk2, tags, T2b, D_, 4*D_, D_/128);
  final_ln_k<<<M2_/4, 256, 0, stream>>>(T2b, ln_s_g, ln_s_b, out);
}

// Round 14
// 278.789 us; speedup vs baseline: 1.0356x; 1.0111x over previous
//
#include <hip/hip_runtime.h>
#include <hip/hip_bf16.h>
#include <math.h>

#define B_    4
#define T_    1536
#define DIN_  512
#define D_    512
#define K_    2
#define H_    8
#define BAND_ 24
#define DH_   64
#define M_    (B_*T_)      // 6144 rows
#define M2_   (2*M_)       // both streams batched
#define ALPHA_ 6.0f
#define BETA_  0.5f
#define EPS_   1e-5f

using bf8  = __attribute__((ext_vector_type(8))) short;   // 8 bf16 (4 VGPRs)
using f32x4 = __attribute__((ext_vector_type(4))) float;  // 4 fp32 acc

__device__ __forceinline__ void async_copy16(const void* g, void* l) {
  __builtin_amdgcn_global_load_lds(
      (const __attribute__((address_space(1))) unsigned int*)g,
      (__attribute__((address_space(3))) unsigned int*)l, 16, 0, 0);
}

__device__ __forceinline__ short f2bf(float v) {
  __hip_bfloat16 h = (__hip_bfloat16)v;
  return *(short*)&h;
}
__device__ __forceinline__ float bf2f(short s) {
  union { unsigned u; float f; } c;
  c.u = ((unsigned)(unsigned short)s) << 16;
  return c.f;
}
// XOR-swizzle of 16B chunks within each 64-element column block (bank-conflict fix)
__device__ __forceinline__ int swz64(int row, int col) {
  return (col & ~63) | ((((col >> 3) ^ row) & 7) << 3) | (col & 7);
}
// tanh-form gelu, 7 VALU (2*log2e folded into polynomial), max err ~1e-3
__device__ __forceinline__ float fast_gelu(float x) {
  const float t = fmaf(0.1029504013f, x * x, 2.3021170686f);  // (a x^2 + b)*2*log2e
  const float e = __builtin_amdgcn_exp2f(x * t);              // e^{2u}
  const float r = __builtin_amdgcn_rcpf(e + 1.0f);
  return fmaf(-x, r, x);
}
// 64-lane butterfly sum
__device__ __forceinline__ float wave_sum(float s) {
#pragma unroll
  for (int o = 1; o < 64; o <<= 1) s += __shfl_xor(s, o);
  return s;
}

// ---------------- bf16 MFMA GEMM: C = A[M,Kd] @ Bt[N,Kd]^T + bias (+res) (+gelu) (+tag)
// A and Bt chunk-swizzled (per 64-element K-block). FLAGS: 1=gelu, 2=bf16 out,
// 4=swizzled out, 8=bf16 residual, 16=fp32 residual, 32=speaker tag.
// TRANSPOSED-ACC epilogue: mfma(bF, aF) => out row = l15, col = quad*4+reg.
template<int BM, int BN, int NI, int NJ, int BK, int FLAGS>
__global__ __launch_bounds__(256) void gemm_bt_t(
    const short* __restrict__ A, const short* __restrict__ Bt,
    const float* __restrict__ bias, const void* __restrict__ res,
    const float* __restrict__ tag2,
    void* __restrict__ Cout, int M, int N, int Kd, int gx) {
  constexpr int CPR  = BK / 8;          // 16B chunks per row
  constexpr int CLOG = (BK == 128) ? 4 : 3;
  __shared__ short lA[BM * BK];
  __shared__ short lB[BN * BK];
  const int gy   = gridDim.x / gx;
  const int xcd  = blockIdx.x & 7;
  const int seq  = blockIdx.x >> 3;
  const int rpx  = gy >> 3;                 // row-tiles per XCD
  const int by   = xcd * rpx + seq / gx;
  const int bx   = seq % gx;
  const int tid  = threadIdx.x;
  const int wave = tid >> 6, lane = tid & 63;
  const int block_m = by * BM, block_n = bx * BN;
  const int wm = (wave & 1) * (BM / 2), wn = (wave >> 1) * (BN / 2);
  const int l15 = lane & 15, quad = lane >> 4, l7 = lane & 7;
  f32x4 acc[NI][NJ] = {};

  for (int k0 = 0; k0 < Kd; k0 += BK) {
    __syncthreads();               // previous step's LDS reads complete
#pragma unroll
    for (int i = 0; i < (BM * CPR) / 256; ++i) {
      const int cb = wave * (BM * CPR / 4) + i * 64;
      const int c  = cb + lane;                 // chunk of 8 bf16
      async_copy16(A + (size_t)(block_m + (c >> CLOG)) * Kd + k0 + (c & (CPR - 1)) * 8,
                   &lA[cb * 8]);
    }
#pragma unroll
    for (int i = 0; i < (BN * CPR) / 256; ++i) {
      const int cb = wave * (BN * CPR / 4) + i * 64;
      const int c  = cb + lane;
      async_copy16(Bt + (size_t)(block_n + (c >> CLOG)) * Kd + k0 + (c & (CPR - 1)) * 8,
                   &lB[cb * 8]);
    }
    __syncthreads();               // barrier drains vmcnt => LDS tiles ready
#pragma unroll
    for (int ks = 0; ks < BK / 32; ++ks) {
      const int kidx = ks * 4 + quad;
      const int koff = ((kidx & ~7) | ((kidx ^ l7) & 7)) << 3;
      bf8 af[NI], bfr[NJ];
#pragma unroll
      for (int i = 0; i < NI; ++i)
        af[i] = *(const bf8*)&lA[(wm + i * 16 + l15) * BK + koff];
#pragma unroll
      for (int j = 0; j < NJ; ++j)
        bfr[j] = *(const bf8*)&lB[(wn + j * 16 + l15) * BK + koff];
#pragma unroll
      for (int i = 0; i < NI; ++i)
#pragma unroll
        for (int j = 0; j < NJ; ++j)
          acc[i][j] = __builtin_amdgcn_mfma_f32_16x16x32_bf16(bfr[j], af[i], acc[i][j], 0, 0, 0);
    }
  }

  const int half = M >> 1;
#pragma unroll
  for (int i = 0; i < NI; ++i) {
    const int row  = block_m + wm + i * 16 + l15;
    const size_t rowN = (size_t)row * N;
    const int toff = (row >= half) ? N : 0;
#pragma unroll
    for (int j = 0; j < NJ; ++j) {
      const int colb = block_n + wn + j * 16 + quad * 4;
      const float4 bb = *(const float4*)&bias[colb];
      float v0 = acc[i][j][0] + bb.x;
      float v1 = acc[i][j][1] + bb.y;
      float v2 = acc[i][j][2] + bb.z;
      float v3 = acc[i][j][3] + bb.w;
      if constexpr (FLAGS & 8) {
        const short4 rv = *(const short4*)&((const short*)res)[rowN + colb];
        v0 += bf2f(rv.x); v1 += bf2f(rv.y); v2 += bf2f(rv.z); v3 += bf2f(rv.w);
      }
      if constexpr (FLAGS & 16) {
        const float4 rv = *(const float4*)&((const float*)res)[rowN + colb];
        v0 += rv.x; v1 += rv.y; v2 += rv.z; v3 += rv.w;
      }
      if constexpr (FLAGS & 32) {
        const float4 tg = *(const float4*)&tag2[toff + colb];
        v0 += tg.x; v1 += tg.y; v2 += tg.z; v3 += tg.w;
      }
      if constexpr (FLAGS & 1) {
        v0 = fast_gelu(v0); v1 = fast_gelu(v1);
        v2 = fast_gelu(v2); v3 = fast_gelu(v3);
      }
      if constexpr (FLAGS & 2) {
        const int oc = (FLAGS & 4) ? swz64(row, colb) : colb;
        short4 o;
        o.x = f2bf(v0); o.y = f2bf(v1); o.z = f2bf(v2); o.w = f2bf(v3);
        *(short4*)&((short*)Cout)[rowN + oc] = o;
      } else {
        float4 o; o.x = v0; o.y = v1; o.z = v2; o.w = v3;
        *(float4*)&((float*)Cout)[rowN + colb] = o;
      }
    }
  }
}

// ---------------- W1 FFN GEMM: 512-thread 8-wave 256x64 tile, BK=64.
// Mechanism (CONFIRMED R11: W1 47.8 -> <42.6 us): 8 waves/block at 40KB LDS
// raises resident waves/CU 2-4x; short K (8 steps) keeps drains cheap.
// FLAGS: 1=gelu, 4=swizzled out. bf16 out.
template<int FLAGS>
__global__ __launch_bounds__(512) void gemm_ffn_t(
    const short* __restrict__ A, const short* __restrict__ Bt,
    const float* __restrict__ bias, const short* __restrict__ res,
    const float* __restrict__ tag2, short* __restrict__ Cout,
    int N, int Kd, int gx) {
  __shared__ short lA[256 * 64];
  __shared__ short lB[64 * 64];
  const int gy   = gridDim.x / gx;
  const int xcd  = blockIdx.x & 7;
  const int seq  = blockIdx.x >> 3;
  const int rpx  = gy >> 3;
  const int by   = xcd * rpx + seq / gx;
  const int bx   = seq % gx;
  const int tid  = threadIdx.x;
  const int wave = tid >> 6, lane = tid & 63;
  const int block_m = by * 256, block_n = bx * 64;
  const int wm = (wave & 3) * 64, wn = (wave >> 2) * 32;
  const int l15 = lane & 15, quad = lane >> 4, l7 = lane & 7;
  f32x4 acc[4][2] = {};

  for (int k0 = 0; k0 < Kd; k0 += 64) {
    __syncthreads();
#pragma unroll
    for (int i = 0; i < 4; ++i) {
      const int cb = wave * 256 + i * 64;
      const int c  = cb + lane;
      async_copy16(A + (size_t)(block_m + (c >> 3)) * Kd + k0 + (c & 7) * 8,
                   &lA[cb * 8]);
    }
    {
      const int cb = wave * 64;
      const int c  = cb + lane;
      async_copy16(Bt + (size_t)(block_n + (c >> 3)) * Kd + k0 + (c & 7) * 8,
                   &lB[cb * 8]);
    }
    __syncthreads();
#pragma unroll
    for (int ks = 0; ks < 2; ++ks) {
      const int koff = (((ks * 4 + quad) ^ l7) << 3);
      bf8 af[4], bfr[2];
#pragma unroll
      for (int i = 0; i < 4; ++i)
        af[i] = *(const bf8*)&lA[(wm + i * 16 + l15) * 64 + koff];
#pragma unroll
      for (int j = 0; j < 2; ++j)
        bfr[j] = *(const bf8*)&lB[(wn + j * 16 + l15) * 64 + koff];
#pragma unroll
      for (int i = 0; i < 4; ++i)
#pragma unroll
        for (int j = 0; j < 2; ++j)
          acc[i][j] = __builtin_amdgcn_mfma_f32_16x16x32_bf16(bfr[j], af[i], acc[i][j], 0, 0, 0);
    }
  }

#pragma unroll
  for (int i = 0; i < 4; ++i) {
    const int row  = block_m + wm + i * 16 + l15;
    const size_t rowN = (size_t)row * N;
    const int toff = (row >= M_) ? N : 0;
#pragma unroll
    for (int j = 0; j < 2; ++j) {
      const int colb = block_n + wn + j * 16 + quad * 4;
      const float4 bb = *(const float4*)&bias[colb];
      float v0 = acc[i][j][0] + bb.x;
      float v1 = acc[i][j][1] + bb.y;
      float v2 = acc[i][j][2] + bb.z;
      float v3 = acc[i][j][3] + bb.w;
      if constexpr (FLAGS & 8) {
        const short4 rv = *(const short4*)&res[rowN + colb];
        v0 += bf2f(rv.x); v1 += bf2f(rv.y); v2 += bf2f(rv.z); v3 += bf2f(rv.w);
      }
      if constexpr (FLAGS & 32) {
        const float4 tg = *(const float4*)&tag2[toff + colb];
        v0 += tg.x; v1 += tg.y; v2 += tg.z; v3 += tg.w;
      }
      if constexpr (FLAGS & 1) {
        v0 = fast_gelu(v0); v1 = fast_gelu(v1);
        v2 = fast_gelu(v2); v3 = fast_gelu(v3);
      }
      const int oc = (FLAGS & 4) ? swz64(row, colb) : colb;
      short4 o;
      o.x = f2bf(v0); o.y = f2bf(v1); o.z = f2bf(v2); o.w = f2bf(v3);
      *(short4*)&Cout[rowN + oc] = o;
    }
  }
}

// ---------------- 512-thread 8-wave 128x128 tile, BK=128 GEMM (Wo + W2).
// Combines BOTH confirmed mechanisms: few drains (BK=128) AND 8 waves/block
// @64KB LDS -> 2 blocks/CU = 16 waves/CU (256-thread versions measured 13%
// occupancy / ~4 waves). FLAGS: 8=bf16 residual, 32=speaker tag. bf16 out,
// unswizzled.
template<int FLAGS>
__global__ __launch_bounds__(512) void gemm_ffn2_t(
    const short* __restrict__ A, const short* __restrict__ Bt,
    const float* __restrict__ bias, const short* __restrict__ res,
    const float* __restrict__ tag2, short* __restrict__ Cout,
    int N, int Kd, int gx) {
  __shared__ short lA[128 * 128];
  __shared__ short lB[128 * 128];
  const int gy   = gridDim.x / gx;
  const int xcd  = blockIdx.x & 7;
  const int seq  = blockIdx.x >> 3;
  const int rpx  = gy >> 3;
  const int by   = xcd * rpx + seq / gx;
  const int bx   = seq % gx;
  const int tid  = threadIdx.x;
  const int wave = tid >> 6, lane = tid & 63;
  const int block_m = by * 128, block_n = bx * 128;
  const int wm = (wave & 1) * 64, wn = (wave >> 1) * 32;
  const int l15 = lane & 15, quad = lane >> 4, l7 = lane & 7;
  f32x4 acc[4][2] = {};

  for (int k0 = 0; k0 < Kd; k0 += 128) {
    __syncthreads();
#pragma unroll
    for (int i = 0; i < 4; ++i) {       // A: 128 rows x 16 chunks = 2048 / 512t
      const int cb = wave * 256 + i * 64;
      const int c  = cb + lane;
      async_copy16(A + (size_t)(block_m + (c >> 4)) * Kd + k0 + (c & 15) * 8,
                   &lA[cb * 8]);
    }
#pragma unroll
    for (int i = 0; i < 4; ++i) {       // B: same shape
      const int cb = wave * 256 + i * 64;
      const int c  = cb + lane;
      async_copy16(Bt + (size_t)(block_n + (c >> 4)) * Kd + k0 + (c & 15) * 8,
                   &lB[cb * 8]);
    }
    __syncthreads();
#pragma unroll
    for (int ks = 0; ks < 4; ++ks) {
      const int kidx = ks * 4 + quad;
      const int koff = ((kidx & ~7) | ((kidx ^ l7) & 7)) << 3;
      bf8 af[4], bfr[2];
#pragma unroll
      for (int i = 0; i < 4; ++i)
        af[i] = *(const bf8*)&lA[(wm + i * 16 + l15) * 128 + koff];
#pragma unroll
      for (int j = 0; j < 2; ++j)
        bfr[j] = *(const bf8*)&lB[(wn + j * 16 + l15) * 128 + koff];
#pragma unroll
      for (int i = 0; i < 4; ++i)
#pragma unroll
        for (int j = 0; j < 2; ++j)
          acc[i][j] = __builtin_amdgcn_mfma_f32_16x16x32_bf16(bfr[j], af[i], acc[i][j], 0, 0, 0);
    }
  }

#pragma unroll
  for (int i = 0; i < 4; ++i) {
    const int row  = block_m + wm + i * 16 + l15;
    const size_t rowN = (size_t)row * N;
    const int toff = (row >= M_) ? N : 0;
#pragma unroll
    for (int j = 0; j < 2; ++j) {
      const int colb = block_n + wn + j * 16 + quad * 4;
      const float4 bb = *(const float4*)&bias[colb];
      float v0 = acc[i][j][0] + bb.x;
      float v1 = acc[i][j][1] + bb.y;
      float v2 = acc[i][j][2] + bb.z;
      float v3 = acc[i][j][3] + bb.w;
      if constexpr (FLAGS & 8) {
        const short4 rv = *(const short4*)&res[rowN + colb];
        v0 += bf2f(rv.x); v1 += bf2f(rv.y); v2 += bf2f(rv.z); v3 += bf2f(rv.w);
      }
      if constexpr (FLAGS & 32) {
        const float4 tg = *(const float4*)&tag2[toff + colb];
        v0 += tg.x; v1 += tg.y; v2 += tg.z; v3 += tg.w;
      }
      short4 o;
      o.x = f2bf(v0); o.y = f2bf(v1); o.z = f2bf(v2); o.w = f2bf(v3);
      *(short4*)&Cout[rowN + colb] = o;
    }
  }
}

// ---- shared 128x128 FLAGS=2 core (bf16 out, bias only), BK=64 single-buffer
// (round-3 proven; used by the dual KV/Q kernel)
__device__ __forceinline__ void gemm128_core(
    const short* __restrict__ A, const short* __restrict__ Bt,
    const float* __restrict__ bias, short* __restrict__ Cout,
    int N, int Kd, int bid, int gx, int gy, short* lA, short* lB) {
  const int xcd  = bid & 7;
  const int seq  = bid >> 3;
  const int rpx  = gy >> 3;
  const int by   = xcd * rpx + seq / gx;
  const int bx   = seq % gx;
  const int tid  = threadIdx.x;
  const int wave = tid >> 6, lane = tid & 63;
  const int block_m = by * 128, block_n = bx * 128;
  const int wm = (wave & 1) * 64, wn = (wave >> 1) * 64;
  const int l15 = lane & 15, quad = lane >> 4, l7 = lane & 7;
  f32x4 acc[4][4] = {};

  for (int k0 = 0; k0 < Kd; k0 += 64) {
    __syncthreads();
#pragma unroll
    for (int i = 0; i < 4; ++i) {
      const int cb = wave * 256 + i * 64;
      const int c  = cb + lane;
      async_copy16(A + (size_t)(block_m + (c >> 3)) * Kd + k0 + (c & 7) * 8,
                   &lA[cb * 8]);
    }
#pragma unroll
    for (int i = 0; i < 4; ++i) {
      const int cb = wave * 256 + i * 64;
      const int c  = cb + lane;
      async_copy16(Bt + (size_t)(block_n + (c >> 3)) * Kd + k0 + (c & 7) * 8,
                   &lB[cb * 8]);
    }
    __syncthreads();
#pragma unroll
    for (int ks = 0; ks < 2; ++ks) {
      bf8 af[4], bfr[4];
#pragma unroll
      for (int i = 0; i < 4; ++i)
        af[i] = *(const bf8*)&lA[(wm + i * 16 + l15) * 64 + (((ks * 4 + quad) ^ l7) << 3)];
#pragma unroll
      for (int j = 0; j < 4; ++j)
        bfr[j] = *(const bf8*)&lB[(wn + j * 16 + l15) * 64 + (((ks * 4 + quad) ^ l7) << 3)];
#pragma unroll
      for (int i = 0; i < 4; ++i)
#pragma unroll
        for (int j = 0; j < 4; ++j)
          acc[i][j] = __builtin_amdgcn_mfma_f32_16x16x32_bf16(bfr[j], af[i], acc[i][j], 0, 0, 0);
    }
  }

#pragma unroll
  for (int i = 0; i < 4; ++i) {
    const int row  = block_m + wm + i * 16 + l15;
    const size_t rowN = (size_t)row * N;
#pragma unroll
    for (int j = 0; j < 4; ++j) {
      const int colb = block_n + wn + j * 16 + quad * 4;
      const float4 bb = *(const float4*)&bias[colb];
      short4 o;
      o.x = f2bf(acc[i][j][0] + bb.x);
      o.y = f2bf(acc[i][j][1] + bb.y);
      o.z = f2bf(acc[i][j][2] + bb.z);
      o.w = f2bf(acc[i][j][3] + bb.w);
      *(short4*)&Cout[rowN + colb] = o;
    }
  }
}

// ---- dual GEMM: first nb0 blocks = GEMM0 (KV), rest = GEMM1 (Q). One launch,
// perfect 3-blocks/CU balance instead of two 1.5-blocks/CU launches with tails.
__global__ __launch_bounds__(256) void gemm_dual_k(
    const short* __restrict__ A0, const short* __restrict__ Bt0,
    const float* __restrict__ bias0, short* __restrict__ C0, int N0, int nb0, int gx0,
    const short* __restrict__ A1, const short* __restrict__ Bt1,
    const float* __restrict__ bias1, short* __restrict__ C1, int N1, int gx1) {
  __shared__ short lA[128 * 64];
  __shared__ short lB[128 * 64];
  const int bid = blockIdx.x;
  if (bid < nb0) {
    gemm128_core(A0, Bt0, bias0, C0, N0, D_, bid, gx0, nb0 / gx0, lA, lB);
  } else {
    const int b1 = bid - nb0;
    const int nb1 = gridDim.x - nb0;
    gemm128_core(A1, Bt1, bias1, C1, N1, D_, b1, gx1, nb1 / gx1, lA, lB);
  }
}

// ---------------- merged prep: x_m cast (swizzled) + 7 weight transposes + bias concat
__device__ __forceinline__ void tconv_tile(const float* __restrict__ W,
                                           short* __restrict__ Wt, int K, int N,
                                           int bx, int by, int tid, float (*s)[33]) {
  const int tx = tid & 31, ty = tid >> 5;
  const int k0 = by * 32, n0 = bx * 32;
#pragma unroll
  for (int r = 0; r < 4; ++r)
    s[ty * 4 + r][tx] = W[(size_t)(k0 + ty * 4 + r) * N + n0 + tx];
  __syncthreads();
#pragma unroll
  for (int r = 0; r < 4; ++r) {
    const int n = n0 + ty * 4 + r;
    Wt[(size_t)n * K + swz64(n, k0 + tx)] = f2bf(s[tx][ty * 4 + r]);
  }
}

__global__ __launch_bounds__(256) void prep_k(
    const float* __restrict__ x_m, short* __restrict__ xb,
    const float* __restrict__ W_in, short* __restrict__ WtIn,
    const float* __restrict__ Wq,  short* __restrict__ WtQ,
    const float* __restrict__ Wk,  const float* __restrict__ Wv,
    short* __restrict__ WtKV,
    const float* __restrict__ Wo,  short* __restrict__ WtO,
    const float* __restrict__ W1,  short* __restrict__ Wt1,
    const float* __restrict__ W2,  short* __restrict__ Wt2,
    const float* __restrict__ bk,  const float* __restrict__ bv,
    float* __restrict__ bkv) {
  __shared__ float s[32][33];
  const int blk = blockIdx.x, tid = threadIdx.x;
  if (blk < 3072) {                       // x_m -> bf16 swizzled (float4 per thread)
    const int e = (blk * 256 + tid) * 4;
    const int row = e >> 9, col = e & 511;
    const float4 v = *(const float4*)&x_m[e];
    short4 o;
    o.x = f2bf(v.x); o.y = f2bf(v.y); o.z = f2bf(v.z); o.w = f2bf(v.w);
    *(short4*)&xb[((size_t)row << 9) | swz64(row, col)] = o;
  } else if (blk < 3328) {                // W_in [512,512]
    const int t = blk - 3072; tconv_tile(W_in, WtIn, DIN_, D_, t & 15, t >> 4, tid, s);
  } else if (blk < 3584) {                // Wq
    const int t = blk - 3328; tconv_tile(Wq, WtQ, D_, D_, t & 15, t >> 4, tid, s);
  } else if (blk < 3840) {                // Wk -> WtKV[0:512]
    const int t = blk - 3584; tconv_tile(Wk, WtKV, D_, D_, t & 15, t >> 4, tid, s);
  } else if (blk < 4096) {                // Wv -> WtKV[512:1024]
    const int t = blk - 3840; tconv_tile(Wv, WtKV + (size_t)D_ * D_, D_, D_, t & 15, t >> 4, tid, s);
  } else if (blk < 4352) {                // Wo
    const int t = blk - 4096; tconv_tile(Wo, WtO, D_, D_, t & 15, t >> 4, tid, s);
  } else if (blk < 5376) {                // W1 [512,2048]: gx=64
    const int t = blk - 4352; tconv_tile(W1, Wt1, D_, 4 * D_, t & 63, t >> 6, tid, s);
  } else if (blk < 6400) {                // W2 [2048,512]: gx=16
    const int t = blk - 5376; tconv_tile(W2, Wt2, 4 * D_, D_, t & 15, t >> 4, tid, s);
  } else {                                // bias concat (4 blocks)
    const int i = (blk - 6400) * 256 + tid;
    bkv[i] = (i < D_) ? bk[i] : bv[i - D_];
  }
}

// ---------------- LayerNorm, bf16 in: out(bf16, swizzled) = LN(in) * g + b
// one 64-lane wave per row (4 rows/block), bf8 loads, shfl reduce, no barriers
__global__ __launch_bounds__(256) void ln_bf_k(const short* __restrict__ in,
                                               const float* __restrict__ g,
                                               const float* __restrict__ b,
                                               short* __restrict__ out) {
  const int row  = blockIdx.x * 4 + (threadIdx.x >> 6);
  const int lane = threadIdx.x & 63;
  const int c0   = lane * 8;
  const bf8 xv = *(const bf8*)&in[(size_t)row * D_ + c0];
  float v[8];
  float s = 0.0f;
#pragma unroll
  for (int e = 0; e < 8; ++e) { v[e] = bf2f(xv[e]); s += v[e]; }
  const float mean = wave_sum(s) * (1.0f / D_);
  float s2 = 0.0f;
#pragma unroll
  for (int e = 0; e < 8; ++e) { v[e] -= mean; s2 += v[e] * v[e]; }
  const float inv = rsqrtf(wave_sum(s2) * (1.0f / D_) + EPS_);
  const float4 g0 = *(const float4*)&g[c0];
  const float4 g1 = *(const float4*)&g[c0 + 4];
  const float4 b0 = *(const float4*)&b[c0];
  const float4 b1 = *(const float4*)&b[c0 + 4];
  bf8 o;
  o[0] = f2bf(v[0] * inv * g0.x + b0.x);
  o[1] = f2bf(v[1] * inv * g0.y + b0.y);
  o[2] = f2bf(v[2] * inv * g0.z + b0.z);
  o[3] = f2bf(v[3] * inv * g0.w + b0.w);
  o[4] = f2bf(v[4] * inv * g1.x + b1.x);
  o[5] = f2bf(v[5] * inv * g1.y + b1.y);
  o[6] = f2bf(v[6] * inv * g1.z + b1.z);
  o[7] = f2bf(v[7] * inv * g1.w + b1.w);
  *(bf8*)&out[(size_t)row * D_ + swz64(row, c0)] = o;
}

// ---------------- merged KV-LN + gate/Q-LN: rows [0,M) = ln_kv(X) -> KVb (swizzled);
// rows [M,3M) = gate+ln_q: Xk (bf16 unswz) + LNq (swizzled). One launch, no tail.
__global__ __launch_bounds__(256) void ln_gate_k(
    const short* __restrict__ X, const float* __restrict__ Ain,
    const float* __restrict__ gkv, const float* __restrict__ bkvp,
    const float* __restrict__ gq, const float* __restrict__ bqp,
    short* __restrict__ KVb, short* __restrict__ Xk, short* __restrict__ LNq) {
  const int row  = blockIdx.x * 4 + (threadIdx.x >> 6);
  const int lane = threadIdx.x & 63;
  const int c0   = lane * 8;
  float v[8];
  float s = 0.0f;
  if (row < M_) {
    const bf8 xv = *(const bf8*)&X[(size_t)row * D_ + c0];
#pragma unroll
    for (int e = 0; e < 8; ++e) { v[e] = bf2f(xv[e]); s += v[e]; }
    const float mean = wave_sum(s) * (1.0f / D_);
    float s2 = 0.0f;
#pragma unroll
    for (int e = 0; e < 8; ++e) { v[e] -= mean; s2 += v[e] * v[e]; }
    const float inv = rsqrtf(wave_sum(s2) * (1.0f / D_) + EPS_);
    const float4 g0 = *(const float4*)&gkv[c0];
    const float4 g1 = *(const float4*)&gkv[c0 + 4];
    const float4 b0 = *(const float4*)&bkvp[c0];
    const float4 b1 = *(const float4*)&bkvp[c0 + 4];
    bf8 o;
    o[0] = f2bf(v[0] * inv * g0.x + b0.x);
    o[1] = f2bf(v[1] * inv * g0.y + b0.y);
    o[2] = f2bf(v[2] * inv * g0.z + b0.z);
    o[3] = f2bf(v[3] * inv * g0.w + b0.w);
    o[4] = f2bf(v[4] * inv * g1.x + b1.x);
    o[5] = f2bf(v[5] * inv * g1.y + b1.y);
    o[6] = f2bf(v[6] * inv * g1.z + b1.z);
    o[7] = f2bf(v[7] * inv * g1.w + b1.w);
    *(bf8*)&KVb[(size_t)row * D_ + swz64(row, c0)] = o;
  } else {
    const int r2 = row - M_;            // [0, 2M)
    const int kk = r2 / M_, rm = r2 % M_;
    const float a = Ain[(size_t)rm * K_ + kk];
    const float w = __builtin_amdgcn_rcpf(1.0f + __expf(-ALPHA_ * (a - BETA_)));
    const bf8 xv = *(const bf8*)&X[(size_t)rm * D_ + c0];
    bf8 xo;
#pragma unroll
    for (int e = 0; e < 8; ++e) {
      v[e] = bf2f(xv[e]) * w;
      xo[e] = f2bf(v[e]);
      s += v[e];
    }
    *(bf8*)&Xk[(size_t)r2 * D_ + c0] = xo;
    const float mean = wave_sum(s) * (1.0f / D_);
    float s2 = 0.0f;
#pragma unroll
    for (int e = 0; e < 8; ++e) { v[e] -= mean; s2 += v[e] * v[e]; }
    const float inv = rsqrtf(wave_sum(s2) * (1.0f / D_) + EPS_);
    const float4 g0 = *(const float4*)&gq[c0];
    const float4 g1 = *(const float4*)&gq[c0 + 4];
    const float4 b0 = *(const float4*)&bqp[c0];
    const float4 b1 = *(const float4*)&bqp[c0 + 4];
    bf8 o;
    o[0] = f2bf(v[0] * inv * g0.x + b0.x);
    o[1] = f2bf(v[1] * inv * g0.y + b0.y);
    o[2] = f2bf(v[2] * inv * g0.z + b0.z);
    o[3] = f2bf(v[3] * inv * g0.w + b0.w);
    o[4] = f2bf(v[4] * inv * g1.x + b1.x);
    o[5] = f2bf(v[5] * inv * g1.y + b1.y);
    o[6] = f2bf(v[6] * inv * g1.z + b1.z);
    o[7] = f2bf(v[7] * inv * g1.w + b1.w);
    *(bf8*)&LNq[(size_t)r2 * D_ + swz64(r2, c0)] = o;
  }
}

// ---------------- final LN: in = T2b (y+h2+tag, bf16); scatter to concat layout (fp32)
__global__ __launch_bounds__(256) void final_ln_k(
    const short* __restrict__ t2, const float* __restrict__ g,
    const float* __restrict__ b, float* __restrict__ out) {
  const int row  = blockIdx.x * 4 + (threadIdx.x >> 6);
  const int lane = threadIdx.x & 63;
  const int c0   = lane * 8;
  const int kk = row / M_, rm = row % M_;
  const int bb_ = rm / T_, t = rm % T_;
  const size_t orow = (size_t)bb_ * (K_ * T_) + (size_t)kk * T_ + t;
  const bf8 xv = *(const bf8*)&t2[(size_t)row * D_ + c0];
  float v[8];
  float s = 0.0f;
#pragma unroll
  for (int e = 0; e < 8; ++e) { v[e] = bf2f(xv[e]); s += v[e]; }
  const float mean = wave_sum(s) * (1.0f / D_);
  float s2 = 0.0f;
#pragma unroll
  for (int e = 0; e < 8; ++e) { v[e] -= mean; s2 += v[e] * v[e]; }
  const float inv = rsqrtf(wave_sum(s2) * (1.0f / D_) + EPS_);
  const float4 g0 = *(const float4*)&g[c0];
  const float4 g1 = *(const float4*)&g[c0 + 4];
  const float4 b0 = *(const float4*)&b[c0];
  const float4 b1 = *(const float4*)&b[c0 + 4];
  float4 o0, o1;
  o0.x = v[0] * inv * g0.x + b0.x;
  o0.y = v[1] * inv * g0.y + b0.y;
  o0.z = v[2] * inv * g0.z + b0.z;
  o0.w = v[3] * inv * g0.w + b0.w;
  o1.x = v[4] * inv * g1.x + b1.x;
  o1.y = v[5] * inv * g1.y + b1.y;
  o1.z = v[6] * inv * g1.z + b1.z;
  o1.w = v[7] * inv * g1.w + b1.w;
  *(float4*)&out[orow * D_ + c0]     = o0;
  *(float4*)&out[orow * D_ + c0 + 4] = o1;
}

// ---------------- MFMA banded attention, both streams
// q [2M,D] bf16 (unswizzled); KVp [M,2D] bf16 (unswizzled); out bf16 swizzled
// Loaders vectorized to 16B/lane (bf8) — 4x fewer load instructions (G13).
#define QT_  64
#define KT_  (QT_ + 2 * BAND_)   // 112 rows
#define SKQ_ 72                  // row stride (shorts) for sK/sQ/sP (144B = 9*16B aligned)
#define STV_ 136                 // row stride (shorts) for sVt
__global__ __launch_bounds__(256) void attn_mfma_k(
    const short* __restrict__ q, const short* __restrict__ KVp,
    short* __restrict__ out) {
  __shared__ short sK[KT_ * SKQ_];
  __shared__ short sQ[QT_ * SKQ_];
  __shared__ short sVt[DH_ * STV_];     // transposed: [dim][key row]
  __shared__ short sP[4][16 * SKQ_];
  const int t0 = blockIdx.x * QT_;
  const int h  = blockIdx.y;
  const int z  = blockIdx.z;            // kk*B + b
  const int b  = z % B_;
  const int tid = threadIdx.x;
  const int wave = tid >> 6, lane = tid & 63;
  const int r8 = tid >> 3;              // 0..31
  const int c8 = (tid & 7) * 8;         // 16B column offset within 64-wide head slice

  for (int r0 = 0; r0 < KT_; r0 += 32) {
    const int r = r0 + r8;
    if (r < KT_) {
      const int s = t0 - BAND_ + r;
      bf8 kv = {0,0,0,0,0,0,0,0}, vv = {0,0,0,0,0,0,0,0};
      if (s >= 0 && s < T_) {
        const size_t g = (size_t)(b * T_ + s) * (2 * D_) + h * DH_ + c8;
        kv = *(const bf8*)&KVp[g];
        vv = *(const bf8*)&KVp[g + D_];
      }
      *(bf8*)&sK[r * SKQ_ + c8] = kv;
#pragma unroll
      for (int e = 0; e < 8; ++e) sVt[(c8 + e) * STV_ + r] = vv[e];
    }
  }
#pragma unroll
  for (int r0 = 0; r0 < QT_; r0 += 32) {
    const int r = r0 + r8;
    const size_t g = (size_t)(z * T_ + t0 + r) * D_ + h * DH_ + c8;
    *(bf8*)&sQ[r * SKQ_ + c8] = *(const bf8*)&q[g];
  }
  __syncthreads();

  const int qg  = wave * 16;            // query group base (also key window base)
  const int l15 = lane & 15, quad = lane >> 4;

  // ---- S = Q16x64 @ K64x64^T  (8 MFMAs)
  bf8 qa0 = *(const bf8*)&sQ[(qg + l15) * SKQ_ + quad * 8];
  bf8 qa1 = *(const bf8*)&sQ[(qg + l15) * SKQ_ + 32 + quad * 8];
  f32x4 acc[4];
#pragma unroll
  for (int j = 0; j < 4; ++j) {
    const bf8 kb0 = *(const bf8*)&sK[(qg + j * 16 + l15) * SKQ_ + quad * 8];
    const bf8 kb1 = *(const bf8*)&sK[(qg + j * 16 + l15) * SKQ_ + 32 + quad * 8];
    f32x4 z4 = {0.f, 0.f, 0.f, 0.f};
    acc[j] = __builtin_amdgcn_mfma_f32_16x16x32_bf16(qa0, kb0, z4, 0, 0, 0);
    acc[j] = __builtin_amdgcn_mfma_f32_16x16x32_bf16(qa1, kb1, acc[j], 0, 0, 0);
  }

  // ---- banded softmax on C-layout rows (row = quad*4+reg, col = j*16+l15)
#pragma unroll
  for (int reg = 0; reg < 4; ++reg) {
    const int i = quad * 4 + reg;       // query within group
    float sc[4];
    float mx = -1e30f;
#pragma unroll
    for (int j = 0; j < 4; ++j) {
      const int c = j * 16 + l15;       // key within 64-window
      const int s = t0 + qg - BAND_ + c;
      const int rel = c - i;            // in [0,48] when inside band
      const bool valid = (rel >= 0) && (rel <= 2 * BAND_) && (s >= 0) && (s < T_);
      sc[j] = valid ? acc[j][reg] * 0.125f : -1e30f;
      mx = fmaxf(mx, sc[j]);
    }
    for (int o = 1; o < 16; o <<= 1) mx = fmaxf(mx, __shfl_xor(mx, o));
    float p[4], se = 0.0f;
#pragma unroll
    for (int j = 0; j < 4; ++j) {
      p[j] = (sc[j] > -1e29f) ? __expf(sc[j] - mx) : 0.0f;
      se += p[j];
    }
    for (int o = 1; o < 16; o <<= 1) se += __shfl_xor(se, o);
    const float inv = __builtin_amdgcn_rcpf(se);
#pragma unroll
    for (int j = 0; j < 4; ++j)
      sP[wave][i * SKQ_ + j * 16 + l15] = f2bf(p[j] * inv);
  }

  // ---- O = P16x64 @ V64x64  (8 MFMAs; V from transposed LDS)
  const bf8 pa0 = *(const bf8*)&sP[wave][l15 * SKQ_ + quad * 8];
  const bf8 pa1 = *(const bf8*)&sP[wave][l15 * SKQ_ + 32 + quad * 8];
  f32x4 oacc[4] = {};
#pragma unroll
  for (int dt = 0; dt < 4; ++dt) {
    const bf8 vb0 = *(const bf8*)&sVt[(dt * 16 + l15) * STV_ + qg + quad * 8];
    const bf8 vb1 = *(const bf8*)&sVt[(dt * 16 + l15) * STV_ + qg + 32 + quad * 8];
    oacc[dt] = __builtin_amdgcn_mfma_f32_16x16x32_bf16(pa0, vb0, oacc[dt], 0, 0, 0);
    oacc[dt] = __builtin_amdgcn_mfma_f32_16x16x32_bf16(pa1, vb1, oacc[dt], 0, 0, 0);
  }
#pragma unroll
  for (int dt = 0; dt < 4; ++dt)
#pragma unroll
    for (int reg = 0; reg < 4; ++reg) {
      const int i = quad * 4 + reg;
      const int row = t0 + qg + i;
      const int col = h * DH_ + dt * 16 + l15;
      out[(size_t)(z * T_ + row) * D_ + swz64(row, col)] = f2bf(oacc[dt][reg]);
    }
}

extern "C" void kernel_launch(void* const* d_in, const int* in_sizes, int n_in,
                              void* d_out, int out_size, void* d_ws, size_t ws_size,
                              hipStream_t stream) {
  const float* x_m    = (const float*)d_in[0];
  const float* A      = (const float*)d_in[1];
  const float* W_in   = (const float*)d_in[2];
  const float* b_in   = (const float*)d_in[3];
  const float* ln_q_g = (const float*)d_in[4];
  const float* ln_q_b = (const float*)d_in[5];
  const float* ln_kv_g= (const float*)d_in[6];
  const float* ln_kv_b= (const float*)d_in[7];
  const float* Wq     = (const float*)d_in[8];
  const float* bq     = (const float*)d_in[9];
  const float* Wk     = (const float*)d_in[10];
  const float* bk     = (const float*)d_in[11];
  const float* Wv     = (const float*)d_in[12];
  const float* bv     = (const float*)d_in[13];
  const float* Wo     = (const float*)d_in[14];
  const float* bo     = (const float*)d_in[15];
  const float* ln_f_g = (const float*)d_in[16];
  const float* ln_f_b = (const float*)d_in[17];
  const float* W1     = (const float*)d_in[18];
  const float* b1     = (const float*)d_in[19];
  const float* W2     = (const float*)d_in[20];
  const float* b2     = (const float*)d_in[21];
  const float* ln_s_g = (const float*)d_in[22];
  const float* ln_s_b = (const float*)d_in[23];
  const float* tags   = (const float*)d_in[24];
  float* out = (float*)d_out;

  const size_t MD = (size_t)M_ * D_;
  // fp32 buffers
  float* bkv = (float*)d_ws;           // [1024]
  // bf16 buffers
  short* X    = (short*)(bkv + 1024);  // [M,D]  unswizzled
  short* Xk2  = X    + MD;             // [2M,D] gated X, then y (bf16, unswizzled)
  short* LNb2 = Xk2  + 2 * MD;         // [2M,D] q-LN (swizzled), then attn out
  short* qb2  = LNb2 + 2 * MD;         // [2M,D]; first MD also = xb (x_m bf16 swz)
  short* KVpb = qb2  + 2 * MD;         // [M,2D] interleaved K|V (unswizzled)
  short* T2b  = KVpb + 2 * MD;         // [2M,D] y+h2+tag (bf16)
  short* H1b  = T2b  + 2 * MD;         // [2M,4D] swizzled
  short* WtIn = H1b + (size_t)M2_ * 4 * D_;
  short* WtQ  = WtIn + (size_t)D_ * DIN_;
  short* WtKV = WtQ  + (size_t)D_ * D_;        // [2D, D]
  short* WtO  = WtKV + (size_t)2 * D_ * D_;
  short* Wt1  = WtO  + (size_t)D_ * D_;        // [4D, D]
  short* Wt2  = Wt1  + (size_t)4 * D_ * D_;    // [D, 4D]
  short* KVb  = Wt2  + (size_t)4 * D_ * D_;    // [M,D] KV-LN (swizzled) — no alias
  short* xb   = qb2;                   // alias (used before Q GEMM)

  // ---- merged prep: x_m cast + 7 weight transposes + K/V bias concat (1 launch)
  prep_k<<<6404, 256, 0, stream>>>(x_m, xb, W_in, WtIn, Wq, WtQ, Wk, Wv, WtKV,
                                   Wo, WtO, W1, Wt1, W2, Wt2, bk, bv, bkv);

  // X = x_m @ W_in + b_in  (bf16 unswizzled out; BK=128 -> 4 K-steps)
  gemm_bt_t<128,64,4,2,128, 2><<<(D_/64) * (M_/128), 256, 0, stream>>>(
      xb, WtIn, b_in, nullptr, nullptr, X, M_, D_, DIN_, D_/64);

  // merged: KVb = LN_kv(X) (swz); Xk2 = gate(X); LNb2 = LN_q(gate(X)) (swz)
  ln_gate_k<<<(3 * M_) / 4, 256, 0, stream>>>(
      X, A, ln_kv_g, ln_kv_b, ln_q_g, ln_q_b, KVb, Xk2, LNb2);

  // dual GEMM: [KV: KVb @ WtKV -> KVpb (N=1024, 384 blocks)] +
  //            [Q:  LNb2 @ WtQ -> qb2  (N=512, 384 blocks)]  in one 768-block launch
  gemm_dual_k<<<768, 256, 0, stream>>>(
      KVb, WtKV, bkv, KVpb, 2 * D_, ((2*D_)/128) * (M_/128), (2*D_)/128,
      LNb2, WtQ, bq, qb2, D_, D_/128);

  attn_mfma_k<<<dim3(T_/QT_, H_, B_*K_), 256, 0, stream>>>(qb2, KVpb, LNb2);
  // y = attn @ Wo + bo + Xk  (512-thread 128x128 BK=128: same drains as before
  // but 16 waves/CU vs 4 — the R11/R13-confirmed occupancy lever, applied to Wo)
  gemm_ffn2_t<8><<<(D_/128) * (M2_/128), 512, 0, stream>>>(
      LNb2, WtO, bo, Xk2, nullptr, Xk2, D_, D_, D_/128);
  ln_bf_k<<<M2_/4, 256, 0, stream>>>(Xk2, ln_f_g, ln_f_b, LNb2);
  // H1 = gelu(LN @ W1 + b1)  (512-thread 256x64 FFN kernel; confirmed win R11)
  gemm_ffn_t<1|4><<<((4*D_)/64) * (M2_/256), 512, 0, stream>>>(
      LNb2, Wt1, b1, nullptr, nullptr, H1b, 4*D_, D_, (4*D_)/64);
  // T2b = h1 @ W2 + b2 + y + tag  (512-thread 128x128 BK=128; R13 best-total config)
  gemm_ffn2_t<8|32><<<(D_/128) * (M2_/128), 512, 0, stream>>>(
      H1b, Wt2, b2, Xk2, tags, T2b, D_, 4*D_, D_/128);
  final_ln_k<<<M2_/4, 256, 0, stream>>>(T2b, ln_s_g, ln_s_b, out);
}